// Round 1
// baseline (1909.324 us; speedup 1.0000x reference)
//
#include <hip/hip_runtime.h>

#define EE 2048
#define LL 512
#define BBATCH 4
#define HH 32
#define SS 64
#define EPSF 1e-5f
static constexpr size_t NEL = (size_t)BBATCH * LL * EE;  // 4,194,304

typedef __attribute__((ext_vector_type(8))) short short8;
typedef __attribute__((ext_vector_type(4))) float f32x4;

__device__ __forceinline__ unsigned short f2bf(float f) {
  union { float f; unsigned u; } x; x.f = f;
  return (unsigned short)((x.u + 0x7fffu + ((x.u >> 16) & 1u)) >> 16);
}

// ---------------- fp32 -> bf16 conversion (weights) ----------------
__global__ void __launch_bounds__(256) f2bf_kernel(const float* __restrict__ src,
                                                   unsigned short* __restrict__ dst, int n4) {
  int idx = blockIdx.x * 256 + threadIdx.x;
  if (idx >= n4) return;
  float4 v = ((const float4*)src)[idx];
  ushort4 o;
  o.x = f2bf(v.x); o.y = f2bf(v.y); o.z = f2bf(v.z); o.w = f2bf(v.w);
  ((ushort4*)dst)[idx] = o;
}

// ---------------- LayerNorm over E per token ----------------
__global__ void __launch_bounds__(256) ln_kernel(const float* __restrict__ x,
                                                 const float* __restrict__ wt,
                                                 const float* __restrict__ bs,
                                                 float* __restrict__ out) {
  __shared__ float red[4];
  int tid = threadIdx.x;
  size_t base = (size_t)blockIdx.x * EE;
  int e = tid * 8;
  float4 v0 = *(const float4*)&x[base + e];
  float4 v1 = *(const float4*)&x[base + e + 4];
  float s = v0.x + v0.y + v0.z + v0.w + v1.x + v1.y + v1.z + v1.w;
#pragma unroll
  for (int off = 32; off >= 1; off >>= 1) s += __shfl_xor(s, off);
  if ((tid & 63) == 0) red[tid >> 6] = s;
  __syncthreads();
  float mean = (red[0] + red[1] + red[2] + red[3]) * (1.f / EE);
  __syncthreads();
  float d, q = 0.f;
  d = v0.x - mean; q += d * d; d = v0.y - mean; q += d * d;
  d = v0.z - mean; q += d * d; d = v0.w - mean; q += d * d;
  d = v1.x - mean; q += d * d; d = v1.y - mean; q += d * d;
  d = v1.z - mean; q += d * d; d = v1.w - mean; q += d * d;
#pragma unroll
  for (int off = 32; off >= 1; off >>= 1) q += __shfl_xor(q, off);
  if ((tid & 63) == 0) red[tid >> 6] = q;
  __syncthreads();
  float var = (red[0] + red[1] + red[2] + red[3]) * (1.f / EE);
  float rstd = rsqrtf(var + EPSF);
  float4 w0 = *(const float4*)&wt[e], w1 = *(const float4*)&wt[e + 4];
  float4 b0 = *(const float4*)&bs[e], b1 = *(const float4*)&bs[e + 4];
  float4 o0, o1;
  o0.x = (v0.x - mean) * rstd * w0.x + b0.x;
  o0.y = (v0.y - mean) * rstd * w0.y + b0.y;
  o0.z = (v0.z - mean) * rstd * w0.z + b0.z;
  o0.w = (v0.w - mean) * rstd * w0.w + b0.w;
  o1.x = (v1.x - mean) * rstd * w1.x + b1.x;
  o1.y = (v1.y - mean) * rstd * w1.y + b1.y;
  o1.z = (v1.z - mean) * rstd * w1.z + b1.z;
  o1.w = (v1.w - mean) * rstd * w1.w + b1.w;
  *(float4*)&out[base + e] = o0;
  *(float4*)&out[base + e + 4] = o1;
}

// ---------------- MAA: token-shift + small GEMMs + x5 slices + decay w ----------------
// writes x5b: 4 bf16 slices (j=0 ->slot0, j=2 ->slot1, j=3 ->slot2, j=4 ->slot3); wout fp32
__global__ void __launch_bounds__(256) maa_kernel(
    const float* __restrict__ xn, const float* __restrict__ state, const int* __restrict__ ip,
    const float* __restrict__ maa_x, const float* __restrict__ maa_w1,
    const float* __restrict__ maa_w2, const float* __restrict__ maa_stack,
    const float* __restrict__ time_decay, const float* __restrict__ decay_w1,
    const float* __restrict__ decay_w2, unsigned short* __restrict__ x5b,
    float* __restrict__ wout) {
  __shared__ float xnb[EE], sxb[EE], tmp[EE];
  __shared__ float th[160], dt[64];
  int tok = blockIdx.x;
  int b = tok >> 9, t = tok & 511;
  int tid = threadIdx.x;
  int ii = *ip;
  const float* cur = xn + (size_t)tok * EE;
  const float* prev = (t == 0)
      ? (state + ((size_t)b * (2 + SS) + (size_t)(2 + SS) * ii + 1) * EE)
      : (cur - EE);
  for (int e = tid; e < EE; e += 256) {
    float c = cur[e], p = prev[e];
    xnb[e] = c;
    float sx = p - c;
    sxb[e] = sx;
    tmp[e] = c + sx * maa_x[e];  // xxm
  }
  __syncthreads();
  if (tid < 160) {
    float acc = 0.f;
    for (int q = 0; q < EE; q++) acc = fmaf(tmp[q], maa_w1[(size_t)q * 160 + tid], acc);
    th[tid] = tanhf(acc);
  }
  __syncthreads();
  for (int j = 0; j < 5; j++) {
    const int slot = (j == 0) ? 0 : (j == 2) ? 1 : (j == 3) ? 2 : 3;
    for (int e = tid; e < EE; e += 256) {
      float acc = 0.f;
#pragma unroll
      for (int q = 0; q < 32; q++)
        acc = fmaf(th[j * 32 + q], maa_w2[(size_t)(j * 32 + q) * EE + e], acc);
      float x5 = xnb[e] + sxb[e] * (maa_stack[(size_t)j * EE + e] + acc);
      if (j == 1) tmp[e] = x5;  // x5_1 kept fp32 in LDS for decay path
      else x5b[(size_t)slot * NEL + (size_t)tok * EE + e] = f2bf(x5);
    }
  }
  __syncthreads();
  if (tid < 64) {
    float acc = 0.f;
    for (int q = 0; q < EE; q++) acc = fmaf(tmp[q], decay_w1[(size_t)q * 64 + tid], acc);
    dt[tid] = tanhf(acc);
  }
  __syncthreads();
  for (int e = tid; e < EE; e += 256) {
    float acc = time_decay[e];
#pragma unroll
    for (int q = 0; q < 64; q++) acc = fmaf(dt[q], decay_w2[(size_t)q * EE + e], acc);
    wout[(size_t)tok * EE + e] = expf(-expf(acc));
  }
}

// ---------------- bf16 MFMA GEMM: C[m,n] = sum_k A[m,k]*W[n,k], M=N=K=2048 ----------------
// MODE 0: C=acc (f32). 1: C=silu(acc). 2: C=add+acc. 3: C=add+sigmoid(mul)*acc. 4: C=bf16(relu(acc)^2)
template <int MODE>
__global__ void __launch_bounds__(256) gemm_bt(const unsigned short* __restrict__ A,
                                               const unsigned short* __restrict__ W,
                                               void* Cout, const float* addsrc,
                                               const float* mulsrc) {
  constexpr int Kd = 2048, Nd = 2048;
  __shared__ __align__(16) unsigned short As[128 * 32];
  __shared__ __align__(16) unsigned short Bs[128 * 32];
  int tid = threadIdx.x;
  int bm = blockIdx.x, bn = blockIdx.y;
  int wave = tid >> 6, lane = tid & 63;
  int wm = wave >> 1, wn = wave & 1;
  f32x4 acc[4][4] = {};
  int srow = tid >> 2;
  int scol = (tid & 3) * 8;
  const unsigned short* Arow = A + (size_t)(bm * 128 + srow) * Kd + scol;
  const unsigned short* Brow = W + (size_t)(bn * 128 + srow) * Kd + scol;
  const unsigned short* Arow2 = Arow + (size_t)64 * Kd;
  const unsigned short* Brow2 = Brow + (size_t)64 * Kd;
  for (int k0 = 0; k0 < Kd; k0 += 32) {
    uint4 a0 = *(const uint4*)(Arow + k0);
    uint4 a1 = *(const uint4*)(Arow2 + k0);
    uint4 b0 = *(const uint4*)(Brow + k0);
    uint4 b1 = *(const uint4*)(Brow2 + k0);
    __syncthreads();  // prior iteration's ds_reads done before overwrite
    *(uint4*)&As[srow * 32 + scol] = a0;
    *(uint4*)&As[(64 + srow) * 32 + scol] = a1;
    *(uint4*)&Bs[srow * 32 + scol] = b0;
    *(uint4*)&Bs[(64 + srow) * 32 + scol] = b1;
    __syncthreads();
    int kofs = (lane >> 4) * 8;
    int rA = wm * 64 + (lane & 15);
    int rB = wn * 64 + (lane & 15);
    short8 av[4], bv[4];
#pragma unroll
    for (int f = 0; f < 4; f++) {
      av[f] = *(const short8*)&As[(rA + f * 16) * 32 + kofs];
      bv[f] = *(const short8*)&Bs[(rB + f * 16) * 32 + kofs];
    }
#pragma unroll
    for (int fm = 0; fm < 4; fm++)
#pragma unroll
      for (int fn = 0; fn < 4; fn++)
        acc[fm][fn] = __builtin_amdgcn_mfma_f32_16x16x32_bf16(av[fm], bv[fn], acc[fm][fn], 0, 0, 0);
  }
  int m0 = bm * 128 + wm * 64;
  int n0 = bn * 128 + wn * 64;
  int rl = (lane >> 4) * 4;
  int cl = lane & 15;
#pragma unroll
  for (int fm = 0; fm < 4; fm++) {
#pragma unroll
    for (int fn = 0; fn < 4; fn++) {
#pragma unroll
      for (int q = 0; q < 4; q++) {
        int m = m0 + fm * 16 + rl + q;
        int n = n0 + fn * 16 + cl;
        size_t o = (size_t)m * Nd + n;
        float val = acc[fm][fn][q];
        if constexpr (MODE == 0) {
          ((float*)Cout)[o] = val;
        } else if constexpr (MODE == 1) {
          ((float*)Cout)[o] = val / (1.f + expf(-val));
        } else if constexpr (MODE == 2) {
          ((float*)Cout)[o] = addsrc[o] + val;
        } else if constexpr (MODE == 3) {
          ((float*)Cout)[o] = addsrc[o] + val * (1.f / (1.f + expf(-mulsrc[o])));
        } else {
          float rv = fmaxf(val, 0.f);
          ((unsigned short*)Cout)[o] = f2bf(rv * rv);
        }
      }
    }
  }
}

// ---------------- sequential WKV scan: one wave per (b,h) ----------------
__global__ void __launch_bounds__(64) scan_kernel(const float* __restrict__ r,
                                                  const float* __restrict__ k,
                                                  const float* __restrict__ v,
                                                  const float* __restrict__ w,
                                                  const float* __restrict__ state,
                                                  const float* __restrict__ faaaa,
                                                  const int* __restrict__ ip,
                                                  float* __restrict__ att) {
  int bh = blockIdx.x;
  int b = bh >> 5, h = bh & 31;
  int lane = threadIdx.x;  // d
  int ii = *ip;
  const float* sb = state + ((size_t)b * (2 + SS) + (size_t)(2 + SS) * ii + 2) * EE;
  float s_[64];
#pragma unroll
  for (int kk = 0; kk < 64; kk++)
    s_[kk] = sb[(size_t)(2 * h + (kk >> 5)) * EE + (kk & 31) * 64 + lane];
  const float* uf = faaaa + h * 64;
  size_t base = ((size_t)(b * LL)) * EE + h * 64;
  for (int t = 0; t < LL; t++) {
    size_t o = base + (size_t)t * EE;
    float vd = v[o + lane];
    float acc = 0.f;
#pragma unroll
    for (int kk = 0; kk < 64; kk++) {
      float rk = r[o + kk];   // uniform -> s_load
      float kv = k[o + kk];
      float wk = w[o + kk];
      float a = kv * vd;
      acc = fmaf(rk, fmaf(uf[kk], a, s_[kk]), acc);
      s_[kk] = fmaf(wk, s_[kk], a);
    }
    att[o + lane] = acc;
  }
}

// ---------------- GroupNorm (per head) + gate, out bf16 ----------------
__global__ void __launch_bounds__(256) gn_gate_kernel(const float* __restrict__ att,
                                                      const float* __restrict__ g,
                                                      const float* __restrict__ gnw,
                                                      const float* __restrict__ gnb,
                                                      unsigned short* __restrict__ attg) {
  int tok = blockIdx.x, tid = threadIdx.x;
  int h = tid >> 3, j = tid & 7;
  size_t base = (size_t)tok * EE + h * 64 + j * 8;
  int e = h * 64 + j * 8;
  float4 a0 = *(const float4*)&att[base];
  float4 a1 = *(const float4*)&att[base + 4];
  float s = a0.x + a0.y + a0.z + a0.w + a1.x + a1.y + a1.z + a1.w;
  s += __shfl_xor(s, 1); s += __shfl_xor(s, 2); s += __shfl_xor(s, 4);
  float mean = s * (1.f / 64.f);
  float d, q = 0.f;
  d = a0.x - mean; q += d * d; d = a0.y - mean; q += d * d;
  d = a0.z - mean; q += d * d; d = a0.w - mean; q += d * d;
  d = a1.x - mean; q += d * d; d = a1.y - mean; q += d * d;
  d = a1.z - mean; q += d * d; d = a1.w - mean; q += d * d;
  q += __shfl_xor(q, 1); q += __shfl_xor(q, 2); q += __shfl_xor(q, 4);
  float rstd = rsqrtf(q * (1.f / 64.f) + EPSF);
  float4 w0 = *(const float4*)&gnw[e], w1 = *(const float4*)&gnw[e + 4];
  float4 b0 = *(const float4*)&gnb[e], b1 = *(const float4*)&gnb[e + 4];
  float4 g0 = *(const float4*)&g[base], g1 = *(const float4*)&g[base + 4];
  ushort4 o0, o1;
  o0.x = f2bf(((a0.x - mean) * rstd * w0.x + b0.x) * g0.x);
  o0.y = f2bf(((a0.y - mean) * rstd * w0.y + b0.y) * g0.y);
  o0.z = f2bf(((a0.z - mean) * rstd * w0.z + b0.z) * g0.z);
  o0.w = f2bf(((a0.w - mean) * rstd * w0.w + b0.w) * g0.w);
  o1.x = f2bf(((a1.x - mean) * rstd * w1.x + b1.x) * g1.x);
  o1.y = f2bf(((a1.y - mean) * rstd * w1.y + b1.y) * g1.y);
  o1.z = f2bf(((a1.z - mean) * rstd * w1.z + b1.z) * g1.z);
  o1.w = f2bf(((a1.w - mean) * rstd * w1.w + b1.w) * g1.w);
  *(ushort4*)&attg[base] = o0;
  *(ushort4*)&attg[base + 4] = o1;
}

// ---------------- FFN token-shift, out bf16 xk/xr ----------------
__global__ void __launch_bounds__(256) ffn_shift_kernel(const float* __restrict__ xn2,
                                                        const float* __restrict__ state,
                                                        const int* __restrict__ ip,
                                                        const float* __restrict__ mk,
                                                        const float* __restrict__ mr,
                                                        unsigned short* __restrict__ xkb,
                                                        unsigned short* __restrict__ xrb) {
  size_t i4 = (size_t)blockIdx.x * 256 + threadIdx.x;
  size_t e0 = i4 * 4;
  if (e0 >= NEL) return;
  int tok = (int)(e0 >> 11);
  int c = (int)(e0 & 2047);
  int b = tok >> 9, t = tok & 511;
  float4 cur = *(const float4*)&xn2[e0];
  float4 prev;
  if (t == 0) {
    int ii = *ip;
    prev = *(const float4*)&state[((size_t)b * (2 + SS) + (size_t)(2 + SS) * ii + 0) * EE + c];
  } else {
    prev = *(const float4*)&xn2[e0 - EE];
  }
  float4 k4 = *(const float4*)&mk[c];
  float4 r4 = *(const float4*)&mr[c];
  ushort4 ko, ro;
  ko.x = f2bf(cur.x + (prev.x - cur.x) * k4.x);
  ko.y = f2bf(cur.y + (prev.y - cur.y) * k4.y);
  ko.z = f2bf(cur.z + (prev.z - cur.z) * k4.z);
  ko.w = f2bf(cur.w + (prev.w - cur.w) * k4.w);
  ro.x = f2bf(cur.x + (prev.x - cur.x) * r4.x);
  ro.y = f2bf(cur.y + (prev.y - cur.y) * r4.y);
  ro.z = f2bf(cur.z + (prev.z - cur.z) * r4.z);
  ro.w = f2bf(cur.w + (prev.w - cur.w) * r4.w);
  *(ushort4*)&xkb[e0] = ko;
  *(ushort4*)&xrb[e0] = ro;
}

extern "C" void kernel_launch(void* const* d_in, const int* in_sizes, int n_in,
                              void* d_out, int out_size, void* d_ws, size_t ws_size,
                              hipStream_t stream) {
  const float* x = (const float*)d_in[0];
  const float* state = (const float*)d_in[1];
  const float* ln1_w = (const float*)d_in[2];
  const float* ln1_b = (const float*)d_in[3];
  const float* ln2_w = (const float*)d_in[4];
  const float* ln2_b = (const float*)d_in[5];
  const float* maa_x = (const float*)d_in[6];
  const float* maa_w1 = (const float*)d_in[7];
  const float* maa_w2 = (const float*)d_in[8];
  const float* maa_stack = (const float*)d_in[9];
  const float* time_decay = (const float*)d_in[10];
  const float* decay_w1 = (const float*)d_in[11];
  const float* decay_w2 = (const float*)d_in[12];
  const float* faaaa = (const float*)d_in[13];
  const float* Wr = (const float*)d_in[14];
  const float* Wk = (const float*)d_in[15];
  const float* Wv = (const float*)d_in[16];
  const float* Wg = (const float*)d_in[17];
  const float* Wo = (const float*)d_in[18];
  const float* gn_w = (const float*)d_in[19];
  const float* gn_b = (const float*)d_in[20];
  const float* ffn_maa_k = (const float*)d_in[21];
  const float* ffn_maa_r = (const float*)d_in[22];
  const float* fWk = (const float*)d_in[23];
  const float* fWr = (const float*)d_in[24];
  const float* fWv = (const float*)d_in[25];
  const int* ip = (const int*)d_in[26];

  char* ws = (char*)d_ws;
  const size_t MBH = NEL * 2;  // 8 MB bf16 slice
  const size_t MBF = NEL * 4;  // 16 MB f32 slice
  unsigned short* WB = (unsigned short*)ws;                  // 4 slots, 32 MB
  float* xn = (float*)(ws + 4 * MBH);                        // 16 MB (reused: att)
  unsigned short* x5b = (unsigned short*)(ws + 4 * MBH + MBF);  // 4 slices, 32 MB
  float* wbuf = (float*)(ws + 4 * MBH + MBF + 4 * MBH);      // 16 (reused: rr_raw)
  float* rbuf = (float*)(ws + 4 * MBH + MBF + 4 * MBH + 1 * MBF);  // reused: xn2
  float* kbuf = (float*)(ws + 4 * MBH + MBF + 4 * MBH + 2 * MBF);
  float* vbuf = (float*)(ws + 4 * MBH + MBF + 4 * MBH + 3 * MBF);
  float* gbuf = (float*)(ws + 4 * MBH + MBF + 4 * MBH + 4 * MBF);
  // aliases (lifetime-disjoint)
  float* att = xn;
  unsigned short* attg = x5b;          // slot0
  float* xn2 = rbuf;
  unsigned short* xkb = x5b;           // slot0
  unsigned short* xrb = x5b + NEL;     // slot1
  unsigned short* kkb = x5b + 2 * NEL; // slot2
  float* rrraw = wbuf;

  const int thr = 256;
  const int nconv = (int)(NEL / 4);
  dim3 gg(16, 16);

  // weights batch 1: Wk,Wv,Wr,Wg
  f2bf_kernel<<<4096, thr, 0, stream>>>(Wk, WB + 0 * NEL, nconv);
  f2bf_kernel<<<4096, thr, 0, stream>>>(Wv, WB + 1 * NEL, nconv);
  f2bf_kernel<<<4096, thr, 0, stream>>>(Wr, WB + 2 * NEL, nconv);
  f2bf_kernel<<<4096, thr, 0, stream>>>(Wg, WB + 3 * NEL, nconv);

  ln_kernel<<<BBATCH * LL, thr, 0, stream>>>(x, ln1_w, ln1_b, xn);
  maa_kernel<<<BBATCH * LL, thr, 0, stream>>>(xn, state, ip, maa_x, maa_w1, maa_w2,
                                              maa_stack, time_decay, decay_w1, decay_w2,
                                              x5b, wbuf);
  gemm_bt<0><<<gg, thr, 0, stream>>>(x5b + 0 * NEL, WB + 0 * NEL, kbuf, nullptr, nullptr);
  gemm_bt<0><<<gg, thr, 0, stream>>>(x5b + 1 * NEL, WB + 1 * NEL, vbuf, nullptr, nullptr);
  gemm_bt<0><<<gg, thr, 0, stream>>>(x5b + 2 * NEL, WB + 2 * NEL, rbuf, nullptr, nullptr);
  gemm_bt<1><<<gg, thr, 0, stream>>>(x5b + 3 * NEL, WB + 3 * NEL, gbuf, nullptr, nullptr);

  scan_kernel<<<BBATCH * HH, 64, 0, stream>>>(rbuf, kbuf, vbuf, wbuf, state, faaaa, ip, att);
  gn_gate_kernel<<<BBATCH * LL, thr, 0, stream>>>(att, gbuf, gn_w, gn_b, attg);

  f2bf_kernel<<<4096, thr, 0, stream>>>(Wo, WB + 0 * NEL, nconv);
  gemm_bt<2><<<gg, thr, 0, stream>>>(attg, WB + 0 * NEL, (float*)d_out, x, nullptr);

  ln_kernel<<<BBATCH * LL, thr, 0, stream>>>((const float*)d_out, ln2_w, ln2_b, xn2);
  ffn_shift_kernel<<<4096, thr, 0, stream>>>(xn2, state, ip, ffn_maa_k, ffn_maa_r, xkb, xrb);

  f2bf_kernel<<<4096, thr, 0, stream>>>(fWr, WB + 1 * NEL, nconv);
  f2bf_kernel<<<4096, thr, 0, stream>>>(fWk, WB + 2 * NEL, nconv);
  f2bf_kernel<<<4096, thr, 0, stream>>>(fWv, WB + 3 * NEL, nconv);

  gemm_bt<0><<<gg, thr, 0, stream>>>(xrb, WB + 1 * NEL, rrraw, nullptr, nullptr);
  gemm_bt<4><<<gg, thr, 0, stream>>>(xkb, WB + 2 * NEL, kkb, nullptr, nullptr);
  gemm_bt<3><<<gg, thr, 0, stream>>>(kkb, WB + 3 * NEL, (float*)d_out, (const float*)d_out, rrraw);
}

// Round 3
// 906.323 us; speedup vs baseline: 2.1067x; 2.1067x over previous
//
#include <hip/hip_runtime.h>

#define EE 2048
#define LL 512
#define BBATCH 4
#define HH 32
#define SS 64
#define EPSF 1e-5f
static constexpr size_t NEL = (size_t)BBATCH * LL * EE;  // 4,194,304

typedef __attribute__((ext_vector_type(8))) short short8;
typedef __attribute__((ext_vector_type(4))) float f32x4;

__device__ __forceinline__ unsigned short f2bf(float f) {
  union { float f; unsigned u; } x; x.f = f;
  return (unsigned short)((x.u + 0x7fffu + ((x.u >> 16) & 1u)) >> 16);
}

// ---------------- fp32 -> bf16 conversion ----------------
__global__ void __launch_bounds__(256) f2bf_kernel(const float* __restrict__ src,
                                                   unsigned short* __restrict__ dst, int n4) {
  int idx = blockIdx.x * 256 + threadIdx.x;
  if (idx >= n4) return;
  float4 v = ((const float4*)src)[idx];
  ushort4 o;
  o.x = f2bf(v.x); o.y = f2bf(v.y); o.z = f2bf(v.z); o.w = f2bf(v.w);
  ((ushort4*)dst)[idx] = o;
}

// ---------------- transpose + zero-pad, f32 src -> bf16 dst[n][K] ----------------
__global__ void __launch_bounds__(256) tp_pad_kernel(const float* __restrict__ src,
                                                     unsigned short* __restrict__ dst,
                                                     int srcld, int K, int nreal, int kreal) {
  int n = blockIdx.y;
  int k = blockIdx.x * 256 + threadIdx.x;
  if (k >= K) return;
  float v = (n < nreal && k < kreal) ? src[(size_t)k * srcld + n] : 0.f;
  dst[(size_t)n * K + k] = f2bf(v);
}

// ---------------- maa_w2 -> block-diagonal concat weight [10240][160] bf16 ----------------
__global__ void __launch_bounds__(256) w2cat_kernel(const float* __restrict__ w2,
                                                    unsigned short* __restrict__ dst) {
  int id = blockIdx.x * 256 + threadIdx.x;
  if (id >= 10240 * 160) return;
  int n = id / 160, kq = id - n * 160;
  int j = n >> 11, e = n & 2047;
  float v = ((kq >> 5) == j) ? w2[(size_t)kq * 2048 + e] : 0.f;
  dst[id] = f2bf(v);
}

// ---------------- LayerNorm over E per token ----------------
__global__ void __launch_bounds__(256) ln_kernel(const float* __restrict__ x,
                                                 const float* __restrict__ wt,
                                                 const float* __restrict__ bs,
                                                 float* __restrict__ out) {
  __shared__ float red[4];
  int tid = threadIdx.x;
  size_t base = (size_t)blockIdx.x * EE;
  int e = tid * 8;
  float4 v0 = *(const float4*)&x[base + e];
  float4 v1 = *(const float4*)&x[base + e + 4];
  float s = v0.x + v0.y + v0.z + v0.w + v1.x + v1.y + v1.z + v1.w;
#pragma unroll
  for (int off = 32; off >= 1; off >>= 1) s += __shfl_xor(s, off);
  if ((tid & 63) == 0) red[tid >> 6] = s;
  __syncthreads();
  float mean = (red[0] + red[1] + red[2] + red[3]) * (1.f / EE);
  __syncthreads();
  float d, q = 0.f;
  d = v0.x - mean; q += d * d; d = v0.y - mean; q += d * d;
  d = v0.z - mean; q += d * d; d = v0.w - mean; q += d * d;
  d = v1.x - mean; q += d * d; d = v1.y - mean; q += d * d;
  d = v1.z - mean; q += d * d; d = v1.w - mean; q += d * d;
#pragma unroll
  for (int off = 32; off >= 1; off >>= 1) q += __shfl_xor(q, off);
  if ((tid & 63) == 0) red[tid >> 6] = q;
  __syncthreads();
  float var = (red[0] + red[1] + red[2] + red[3]) * (1.f / EE);
  float rstd = rsqrtf(var + EPSF);
  float4 w0 = *(const float4*)&wt[e], w1 = *(const float4*)&wt[e + 4];
  float4 b0 = *(const float4*)&bs[e], b1 = *(const float4*)&bs[e + 4];
  float4 o0, o1;
  o0.x = (v0.x - mean) * rstd * w0.x + b0.x;
  o0.y = (v0.y - mean) * rstd * w0.y + b0.y;
  o0.z = (v0.z - mean) * rstd * w0.z + b0.z;
  o0.w = (v0.w - mean) * rstd * w0.w + b0.w;
  o1.x = (v1.x - mean) * rstd * w1.x + b1.x;
  o1.y = (v1.y - mean) * rstd * w1.y + b1.y;
  o1.z = (v1.z - mean) * rstd * w1.z + b1.z;
  o1.w = (v1.w - mean) * rstd * w1.w + b1.w;
  *(float4*)&out[base + e] = o0;
  *(float4*)&out[base + e + 4] = o1;
}

// ---------------- token-shift: xxm bf16 + sx f32 ----------------
__global__ void __launch_bounds__(256) shift_kernel(const float* __restrict__ xn,
                                                    const float* __restrict__ state,
                                                    const int* __restrict__ ip,
                                                    const float* __restrict__ maa_x,
                                                    unsigned short* __restrict__ xxm,
                                                    float* __restrict__ sx) {
  int tok = blockIdx.x;
  int b = tok >> 9, t = tok & 511;
  int tid = threadIdx.x;
  const float* cur = xn + (size_t)tok * EE;
  const float* prev = (t == 0)
      ? (state + ((size_t)b * (2 + SS) + (size_t)(2 + SS) * (*ip) + 1) * EE)
      : (cur - EE);
  int e = tid * 8;
#pragma unroll
  for (int half = 0; half < 2; ++half) {
    int eh = e + half * 4;
    float4 c = *(const float4*)&cur[eh];
    float4 p = *(const float4*)&prev[eh];
    float4 mx = *(const float4*)&maa_x[eh];
    float4 sv;
    sv.x = p.x - c.x; sv.y = p.y - c.y; sv.z = p.z - c.z; sv.w = p.w - c.w;
    *(float4*)&sx[(size_t)tok * EE + eh] = sv;
    ushort4 xo;
    xo.x = f2bf(c.x + sv.x * mx.x);
    xo.y = f2bf(c.y + sv.y * mx.y);
    xo.z = f2bf(c.z + sv.z * mx.z);
    xo.w = f2bf(c.w + sv.w * mx.w);
    *(ushort4*)&xxm[(size_t)tok * EE + eh] = xo;
  }
}

// ---------------- generic bf16 MFMA GEMM: C[m,n] = sum_k A[m,k]*W[n,k], M=2048 ----------------
// MODE 0: f32 acc. 1: f32 silu. 2: f32 addsrc+acc. 3: f32 addsrc+sigmoid(mulsrc)*acc.
// MODE 4: bf16 relu(acc)^2. 5: bf16 tanh(acc). 6: f32 exp(-exp(td[n]+acc)). 7: x5-assemble.
template <int MODE>
__global__ void __launch_bounds__(256) gemm_bt(const unsigned short* __restrict__ A, int lda,
                                               const unsigned short* __restrict__ W, int ldw,
                                               int K, int NB,
                                               void* __restrict__ Cout, int ldc,
                                               const float* __restrict__ p1,
                                               const float* __restrict__ p2,
                                               const float* __restrict__ p3) {
  __shared__ __align__(16) unsigned short As[128 * 32];
  __shared__ __align__(16) unsigned short Bs[128 * 32];
  int nwg = gridDim.x, bid = blockIdx.x;
  int qd = nwg >> 3;
  int wg = (bid & 7) * qd + (bid >> 3);  // bijective XCD swizzle (nwg % 8 == 0)
  int bm = wg / NB, bn = wg - bm * NB;
  int tid = threadIdx.x;
  int wave = tid >> 6, lane = tid & 63;
  int wm = wave >> 1, wn = wave & 1;
  f32x4 acc[4][4] = {};
  int srow = tid >> 2;
  int scol = (tid & 3) * 8;
  const unsigned short* Arow = A + (size_t)(bm * 128 + srow) * lda + scol;
  const unsigned short* Brow = W + (size_t)(bn * 128 + srow) * ldw + scol;
  const unsigned short* Arow2 = Arow + (size_t)64 * lda;
  const unsigned short* Brow2 = Brow + (size_t)64 * ldw;
  for (int k0 = 0; k0 < K; k0 += 32) {
    uint4 a0 = *(const uint4*)(Arow + k0);
    uint4 a1 = *(const uint4*)(Arow2 + k0);
    uint4 b0 = *(const uint4*)(Brow + k0);
    uint4 b1 = *(const uint4*)(Brow2 + k0);
    __syncthreads();
    *(uint4*)&As[srow * 32 + scol] = a0;
    *(uint4*)&As[(64 + srow) * 32 + scol] = a1;
    *(uint4*)&Bs[srow * 32 + scol] = b0;
    *(uint4*)&Bs[(64 + srow) * 32 + scol] = b1;
    __syncthreads();
    int kofs = (lane >> 4) * 8;
    int rA = wm * 64 + (lane & 15);
    int rB = wn * 64 + (lane & 15);
    short8 av[4], bv[4];
#pragma unroll
    for (int f = 0; f < 4; f++) {
      av[f] = *(const short8*)&As[(rA + f * 16) * 32 + kofs];
      bv[f] = *(const short8*)&Bs[(rB + f * 16) * 32 + kofs];
    }
#pragma unroll
    for (int fm = 0; fm < 4; fm++)
#pragma unroll
      for (int fn = 0; fn < 4; fn++)
        acc[fm][fn] = __builtin_amdgcn_mfma_f32_16x16x32_bf16(av[fm], bv[fn], acc[fm][fn], 0, 0, 0);
  }
  int m0 = bm * 128 + wm * 64;
  int n0 = bn * 128 + wn * 64;
  int rl = (lane >> 4) * 4;
  int cl = lane & 15;
#pragma unroll
  for (int fm = 0; fm < 4; fm++) {
#pragma unroll
    for (int fn = 0; fn < 4; fn++) {
#pragma unroll
      for (int q = 0; q < 4; q++) {
        int m = m0 + fm * 16 + rl + q;
        int n = n0 + fn * 16 + cl;
        size_t o = (size_t)m * ldc + n;
        float val = acc[fm][fn][q];
        if constexpr (MODE == 0) {
          ((float*)Cout)[o] = val;
        } else if constexpr (MODE == 1) {
          ((float*)Cout)[o] = val / (1.f + expf(-val));
        } else if constexpr (MODE == 2) {
          ((float*)Cout)[o] = p1[o] + val;
        } else if constexpr (MODE == 3) {
          ((float*)Cout)[o] = p1[o] + val * (1.f / (1.f + expf(-p2[o])));
        } else if constexpr (MODE == 4) {
          float rv = fmaxf(val, 0.f);
          ((unsigned short*)Cout)[o] = f2bf(rv * rv);
        } else if constexpr (MODE == 5) {
          ((unsigned short*)Cout)[o] = f2bf(tanhf(val));
        } else if constexpr (MODE == 6) {
          ((float*)Cout)[o] = expf(-expf(p1[n] + val));
        } else {  // MODE 7: x5 assemble: j = n>>11, e = n&2047
          int j = n >> 11, e = n & 2047;
          size_t oe = (size_t)m * EE + e;
          float xv = p1[oe];
          float sv = p2[oe];
          float st = p3[(size_t)j * EE + e];
          ((unsigned short*)Cout)[(size_t)j * NEL + oe] = f2bf(xv + sv * (st + val));
        }
      }
    }
  }
}

// ---------------- sequential WKV scan: 8 waves per (b,h), k split 8-way ----------------
struct SFrag {
  float4 ra, rb, ka, kb, wa, wb;
  float v;
};

// NOTE parameter order (r,k,v,w) matches call sites; R2 bug was w/v swap here.
__device__ __forceinline__ void sload(SFrag& f, const float* __restrict__ r,
                                      const float* __restrict__ k, const float* __restrict__ v,
                                      const float* __restrict__ w, size_t o, int k0, int lane) {
  f.ra = *(const float4*)&r[o + k0];
  f.rb = *(const float4*)&r[o + k0 + 4];
  f.ka = *(const float4*)&k[o + k0];
  f.kb = *(const float4*)&k[o + k0 + 4];
  f.wa = *(const float4*)&w[o + k0];
  f.wb = *(const float4*)&w[o + k0 + 4];
  f.v = v[o + lane];
}

__global__ void __launch_bounds__(512) scan_kernel(const float* __restrict__ r,
                                                   const float* __restrict__ k,
                                                   const float* __restrict__ v,
                                                   const float* __restrict__ w,
                                                   const float* __restrict__ state,
                                                   const float* __restrict__ faaaa,
                                                   const int* __restrict__ ip,
                                                   float* __restrict__ att) {
  __shared__ float part[2][8][64];
  int bh = blockIdx.x;
  int b = bh >> 5, h = bh & 31;
  int wv = threadIdx.x >> 6;
  int lane = threadIdx.x & 63;  // d
  int k0w = wv * 8;
  int ii = *ip;
  const float* sb = state + ((size_t)b * (2 + SS) + (size_t)(2 + SS) * ii + 2) * EE;
  float s0_, s1_, s2_, s3_, s4_, s5_, s6_, s7_;
  {
    const float* p = sb + (size_t)(2 * h + (k0w >> 5)) * EE + (k0w & 31) * 64 + lane;
    s0_ = p[0]; s1_ = p[64]; s2_ = p[128]; s3_ = p[192];
    s4_ = p[256]; s5_ = p[320]; s6_ = p[384]; s7_ = p[448];
  }
  float4 u0 = *(const float4*)&faaaa[h * 64 + k0w];
  float4 u1 = *(const float4*)&faaaa[h * 64 + k0w + 4];
  size_t base = (size_t)b * LL * EE + (size_t)h * 64;
  SFrag cur, nxt;
  sload(cur, r, k, v, w, base, k0w, lane);
  for (int t = 0; t < LL; ++t) {
    int tn = (t < LL - 1) ? t + 1 : t;
    sload(nxt, r, k, v, w, base + (size_t)tn * EE, k0w, lane);
    float vc = cur.v;
    float acc0 = 0.f, acc1 = 0.f, a;
    a = cur.ka.x * vc; acc0 = fmaf(cur.ra.x, fmaf(u0.x, a, s0_), acc0); s0_ = fmaf(cur.wa.x, s0_, a);
    a = cur.ka.y * vc; acc1 = fmaf(cur.ra.y, fmaf(u0.y, a, s1_), acc1); s1_ = fmaf(cur.wa.y, s1_, a);
    a = cur.ka.z * vc; acc0 = fmaf(cur.ra.z, fmaf(u0.z, a, s2_), acc0); s2_ = fmaf(cur.wa.z, s2_, a);
    a = cur.ka.w * vc; acc1 = fmaf(cur.ra.w, fmaf(u0.w, a, s3_), acc1); s3_ = fmaf(cur.wa.w, s3_, a);
    a = cur.kb.x * vc; acc0 = fmaf(cur.rb.x, fmaf(u1.x, a, s4_), acc0); s4_ = fmaf(cur.wb.x, s4_, a);
    a = cur.kb.y * vc; acc1 = fmaf(cur.rb.y, fmaf(u1.y, a, s5_), acc1); s5_ = fmaf(cur.wb.y, s5_, a);
    a = cur.kb.z * vc; acc0 = fmaf(cur.rb.z, fmaf(u1.z, a, s6_), acc0); s6_ = fmaf(cur.wb.z, s6_, a);
    a = cur.kb.w * vc; acc1 = fmaf(cur.rb.w, fmaf(u1.w, a, s7_), acc1); s7_ = fmaf(cur.wb.w, s7_, a);
    float acc = acc0 + acc1;
    if (wv != 0) part[t & 1][wv][lane] = acc;
    __syncthreads();
    if (wv == 0) {
      float tot = acc + part[t & 1][1][lane] + part[t & 1][2][lane] + part[t & 1][3][lane] +
                  part[t & 1][4][lane] + part[t & 1][5][lane] + part[t & 1][6][lane] +
                  part[t & 1][7][lane];
      att[base + (size_t)t * EE + lane] = tot;
    }
    cur = nxt;
  }
}

// ---------------- GroupNorm (per head) + gate, out bf16 ----------------
__global__ void __launch_bounds__(256) gn_gate_kernel(const float* __restrict__ att,
                                                      const float* __restrict__ g,
                                                      const float* __restrict__ gnw,
                                                      const float* __restrict__ gnb,
                                                      unsigned short* __restrict__ attg) {
  int tok = blockIdx.x, tid = threadIdx.x;
  int h = tid >> 3, j = tid & 7;
  size_t base = (size_t)tok * EE + h * 64 + j * 8;
  int e = h * 64 + j * 8;
  float4 a0 = *(const float4*)&att[base];
  float4 a1 = *(const float4*)&att[base + 4];
  float s = a0.x + a0.y + a0.z + a0.w + a1.x + a1.y + a1.z + a1.w;
  s += __shfl_xor(s, 1); s += __shfl_xor(s, 2); s += __shfl_xor(s, 4);
  float mean = s * (1.f / 64.f);
  float d, q = 0.f;
  d = a0.x - mean; q += d * d; d = a0.y - mean; q += d * d;
  d = a0.z - mean; q += d * d; d = a0.w - mean; q += d * d;
  d = a1.x - mean; q += d * d; d = a1.y - mean; q += d * d;
  d = a1.z - mean; q += d * d; d = a1.w - mean; q += d * d;
  q += __shfl_xor(q, 1); q += __shfl_xor(q, 2); q += __shfl_xor(q, 4);
  float rstd = rsqrtf(q * (1.f / 64.f) + EPSF);
  float4 w0 = *(const float4*)&gnw[e], w1 = *(const float4*)&gnw[e + 4];
  float4 b0 = *(const float4*)&gnb[e], b1 = *(const float4*)&gnb[e + 4];
  float4 g0 = *(const float4*)&g[base], g1 = *(const float4*)&g[base + 4];
  ushort4 o0, o1;
  o0.x = f2bf(((a0.x - mean) * rstd * w0.x + b0.x) * g0.x);
  o0.y = f2bf(((a0.y - mean) * rstd * w0.y + b0.y) * g0.y);
  o0.z = f2bf(((a0.z - mean) * rstd * w0.z + b0.z) * g0.z);
  o0.w = f2bf(((a0.w - mean) * rstd * w0.w + b0.w) * g0.w);
  o1.x = f2bf(((a1.x - mean) * rstd * w1.x + b1.x) * g1.x);
  o1.y = f2bf(((a1.y - mean) * rstd * w1.y + b1.y) * g1.y);
  o1.z = f2bf(((a1.z - mean) * rstd * w1.z + b1.z) * g1.z);
  o1.w = f2bf(((a1.w - mean) * rstd * w1.w + b1.w) * g1.w);
  *(ushort4*)&attg[base] = o0;
  *(ushort4*)&attg[base + 4] = o1;
}

// ---------------- FFN token-shift, out bf16 xk/xr ----------------
__global__ void __launch_bounds__(256) ffn_shift_kernel(const float* __restrict__ xn2,
                                                        const float* __restrict__ state,
                                                        const int* __restrict__ ip,
                                                        const float* __restrict__ mk,
                                                        const float* __restrict__ mr,
                                                        unsigned short* __restrict__ xkb,
                                                        unsigned short* __restrict__ xrb) {
  size_t i4 = (size_t)blockIdx.x * 256 + threadIdx.x;
  size_t e0 = i4 * 4;
  if (e0 >= NEL) return;
  int tok = (int)(e0 >> 11);
  int c = (int)(e0 & 2047);
  int b = tok >> 9, t = tok & 511;
  float4 cur = *(const float4*)&xn2[e0];
  float4 prev;
  if (t == 0) {
    int ii = *ip;
    prev = *(const float4*)&state[((size_t)b * (2 + SS) + (size_t)(2 + SS) * ii + 0) * EE + c];
  } else {
    prev = *(const float4*)&xn2[e0 - EE];
  }
  float4 k4 = *(const float4*)&mk[c];
  float4 r4 = *(const float4*)&mr[c];
  ushort4 ko, ro;
  ko.x = f2bf(cur.x + (prev.x - cur.x) * k4.x);
  ko.y = f2bf(cur.y + (prev.y - cur.y) * k4.y);
  ko.z = f2bf(cur.z + (prev.z - cur.z) * k4.z);
  ko.w = f2bf(cur.w + (prev.w - cur.w) * k4.w);
  ro.x = f2bf(cur.x + (prev.x - cur.x) * r4.x);
  ro.y = f2bf(cur.y + (prev.y - cur.y) * r4.y);
  ro.z = f2bf(cur.z + (prev.z - cur.z) * r4.z);
  ro.w = f2bf(cur.w + (prev.w - cur.w) * r4.w);
  *(ushort4*)&xkb[e0] = ko;
  *(ushort4*)&xrb[e0] = ro;
}

extern "C" void kernel_launch(void* const* d_in, const int* in_sizes, int n_in,
                              void* d_out, int out_size, void* d_ws, size_t ws_size,
                              hipStream_t stream) {
  const float* x = (const float*)d_in[0];
  const float* state = (const float*)d_in[1];
  const float* ln1_w = (const float*)d_in[2];
  const float* ln1_b = (const float*)d_in[3];
  const float* ln2_w = (const float*)d_in[4];
  const float* ln2_b = (const float*)d_in[5];
  const float* maa_x = (const float*)d_in[6];
  const float* maa_w1 = (const float*)d_in[7];
  const float* maa_w2 = (const float*)d_in[8];
  const float* maa_stack = (const float*)d_in[9];
  const float* time_decay = (const float*)d_in[10];
  const float* decay_w1 = (const float*)d_in[11];
  const float* decay_w2 = (const float*)d_in[12];
  const float* faaaa = (const float*)d_in[13];
  const float* Wr = (const float*)d_in[14];
  const float* Wk = (const float*)d_in[15];
  const float* Wv = (const float*)d_in[16];
  const float* Wg = (const float*)d_in[17];
  const float* Wo = (const float*)d_in[18];
  const float* gn_w = (const float*)d_in[19];
  const float* gn_b = (const float*)d_in[20];
  const float* ffn_maa_k = (const float*)d_in[21];
  const float* ffn_maa_r = (const float*)d_in[22];
  const float* fWk = (const float*)d_in[23];
  const float* fWr = (const float*)d_in[24];
  const float* fWv = (const float*)d_in[25];
  const int* ip = (const int*)d_in[26];

  char* ws = (char*)d_ws;
  const size_t MB1 = 1024 * 1024;
  unsigned short* WB0 = (unsigned short*)ws;                       // 8 MB
  unsigned short* WB1 = (unsigned short*)(ws + 8 * MB1);           // 8 MB
  float* xn = (float*)(ws + 16 * MB1);                             // 16 MB (also att)
  unsigned short* x5b = (unsigned short*)(ws + 32 * MB1);          // 5 x 8 MB
  float* wbuf = (float*)(ws + 72 * MB1);                           // 16 MB (xxm in low 8)
  float* rbuf = (float*)(ws + 88 * MB1);                           // 16 MB
  float* kbuf = (float*)(ws + 104 * MB1);                          // 16 MB
  float* vbuf = (float*)(ws + 120 * MB1);                          // 16 MB
  float* gbuf = (float*)(ws + 136 * MB1);                          // 16 MB (sx first)
  char* smalls = ws + 152 * MB1;                                   // ~6.8 MB
  unsigned short* th = (unsigned short*)smalls;                    // 2048x256 = 1 MB
  unsigned short* w1T = (unsigned short*)(smalls + 1 * MB1);       // 256x2048 = 1 MB
  unsigned short* w2cat = (unsigned short*)(smalls + 2 * MB1);     // 10240x160 = 3.28 MB
  unsigned short* dw1T = (unsigned short*)(smalls + 5376 * 1024);  // 128x2048 = 0.5 MB
  unsigned short* dw2T = (unsigned short*)(smalls + 5888 * 1024);  // 2048x128 = 0.5 MB
  unsigned short* dt = (unsigned short*)(smalls + 6400 * 1024);    // 2048x128 = 0.5 MB

  unsigned short* xxm = (unsigned short*)wbuf;
  float* sx = gbuf;
  float* att = xn;
  unsigned short* attg = x5b;              // slot0
  float* xn2 = rbuf;
  unsigned short* xkb = x5b + 1 * NEL;     // slot1
  unsigned short* xrb = x5b + 2 * NEL;     // slot2
  unsigned short* kkb = x5b + 3 * NEL;     // slot3
  float* rrraw = wbuf;

  const int thr = 256;
  const int nconv = (int)(NEL / 4);

  // 1. LN1
  ln_kernel<<<BBATCH * LL, thr, 0, stream>>>(x, ln1_w, ln1_b, xn);
  // 2. token shift -> xxm bf16, sx f32
  shift_kernel<<<BBATCH * LL, thr, 0, stream>>>(xn, state, ip, maa_x, xxm, sx);
  // 3. weight preps
  tp_pad_kernel<<<dim3(8, 256), thr, 0, stream>>>(maa_w1, w1T, 160, 2048, 160, 2048);
  w2cat_kernel<<<6400, thr, 0, stream>>>(maa_w2, w2cat);
  tp_pad_kernel<<<dim3(8, 128), thr, 0, stream>>>(decay_w1, dw1T, 64, 2048, 64, 2048);
  tp_pad_kernel<<<dim3(1, 2048), thr, 0, stream>>>(decay_w2, dw2T, 2048, 128, 2048, 64);
  // 4. th = tanh(xxm @ w1T): N=256, grid 32
  gemm_bt<5><<<32, thr, 0, stream>>>(xxm, 2048, w1T, 2048, 2048, 2, th, 256, nullptr, nullptr, nullptr);
  // 5. x5 assemble GEMM: N=10240, K=160, grid 1280
  gemm_bt<7><<<1280, thr, 0, stream>>>(th, 256, w2cat, 160, 160, 80, x5b, 0, xn, sx, maa_stack);
  // 6. dt = tanh(x5_1 @ dw1T): N=128, grid 16
  gemm_bt<5><<<16, thr, 0, stream>>>(x5b + 1 * NEL, 2048, dw1T, 2048, 2048, 1, dt, 128, nullptr, nullptr, nullptr);
  // 7. w = exp(-exp(td + dt @ dw2T)): K=128, grid 256
  gemm_bt<6><<<256, thr, 0, stream>>>(dt, 128, dw2T, 128, 128, 16, wbuf, 2048, time_decay, nullptr, nullptr);
  // 8-11. k, v, r, g projections (weight conversion ping-pong)
  f2bf_kernel<<<4096, thr, 0, stream>>>(Wk, WB0, nconv);
  gemm_bt<0><<<256, thr, 0, stream>>>(x5b + 0 * NEL, 2048, WB0, 2048, 2048, 16, kbuf, 2048, nullptr, nullptr, nullptr);
  f2bf_kernel<<<4096, thr, 0, stream>>>(Wv, WB1, nconv);
  gemm_bt<0><<<256, thr, 0, stream>>>(x5b + 2 * NEL, 2048, WB1, 2048, 2048, 16, vbuf, 2048, nullptr, nullptr, nullptr);
  f2bf_kernel<<<4096, thr, 0, stream>>>(Wr, WB0, nconv);
  gemm_bt<0><<<256, thr, 0, stream>>>(x5b + 3 * NEL, 2048, WB0, 2048, 2048, 16, rbuf, 2048, nullptr, nullptr, nullptr);
  f2bf_kernel<<<4096, thr, 0, stream>>>(Wg, WB1, nconv);
  gemm_bt<1><<<256, thr, 0, stream>>>(x5b + 4 * NEL, 2048, WB1, 2048, 2048, 16, gbuf, 2048, nullptr, nullptr, nullptr);
  // 12. scan
  scan_kernel<<<BBATCH * HH, 512, 0, stream>>>(rbuf, kbuf, vbuf, wbuf, state, faaaa, ip, att);
  // 13. groupnorm + gate
  gn_gate_kernel<<<BBATCH * LL, thr, 0, stream>>>(att, gbuf, gn_w, gn_b, attg);
  // 14. out = x + attg @ Wo^T
  f2bf_kernel<<<4096, thr, 0, stream>>>(Wo, WB0, nconv);
  gemm_bt<2><<<256, thr, 0, stream>>>(attg, 2048, WB0, 2048, 2048, 16, (float*)d_out, 2048, x, nullptr, nullptr);
  // 15. LN2
  ln_kernel<<<BBATCH * LL, thr, 0, stream>>>((const float*)d_out, ln2_w, ln2_b, xn2);
  // 16. FFN shift
  ffn_shift_kernel<<<4096, thr, 0, stream>>>(xn2, state, ip, ffn_maa_k, ffn_maa_r, xkb, xrb);
  // 17. rr raw logits
  f2bf_kernel<<<4096, thr, 0, stream>>>(fWr, WB1, nconv);
  gemm_bt<0><<<256, thr, 0, stream>>>(xrb, 2048, WB1, 2048, 2048, 16, rrraw, 2048, nullptr, nullptr, nullptr);
  // 18. kk = relu(xk @ fWk^T)^2 -> bf16
  f2bf_kernel<<<4096, thr, 0, stream>>>(fWk, WB0, nconv);
  gemm_bt<4><<<256, thr, 0, stream>>>(xkb, 2048, WB0, 2048, 2048, 16, kkb, 2048, nullptr, nullptr, nullptr);
  // 19. out += sigmoid(rr) * (kk @ fWv^T)
  f2bf_kernel<<<4096, thr, 0, stream>>>(fWv, WB1, nconv);
  gemm_bt<3><<<256, thr, 0, stream>>>(kkb, 2048, WB1, 2048, 2048, 16, (float*)d_out, 2048, (const float*)d_out, rrraw, nullptr);
}

// Round 4
// 741.538 us; speedup vs baseline: 2.5748x; 1.2222x over previous
//
#include <hip/hip_runtime.h>

#define EE 2048
#define LL 512
#define BBATCH 4
#define HH 32
#define SS 64
#define EPSF 1e-5f
static constexpr size_t NEL = (size_t)BBATCH * LL * EE;  // 4,194,304

typedef __attribute__((ext_vector_type(8))) short short8;
typedef __attribute__((ext_vector_type(4))) float f32x4;

__device__ __forceinline__ unsigned short f2bf(float f) {
  union { float f; unsigned u; } x; x.f = f;
  return (unsigned short)((x.u + 0x7fffu + ((x.u >> 16) & 1u)) >> 16);
}

__device__ __forceinline__ void gload_lds16(const unsigned short* g, unsigned short* l) {
  __builtin_amdgcn_global_load_lds((const __attribute__((address_space(1))) void*)g,
                                   (__attribute__((address_space(3))) void*)l, 16, 0, 0);
}

// ---------------- fp32 -> bf16 conversion ----------------
__global__ void __launch_bounds__(256) f2bf_kernel(const float* __restrict__ src,
                                                   unsigned short* __restrict__ dst, int n4) {
  int idx = blockIdx.x * 256 + threadIdx.x;
  if (idx >= n4) return;
  float4 v = ((const float4*)src)[idx];
  ushort4 o;
  o.x = f2bf(v.x); o.y = f2bf(v.y); o.z = f2bf(v.z); o.w = f2bf(v.w);
  ((ushort4*)dst)[idx] = o;
}

// ---------------- transpose + zero-pad, f32 src -> bf16 dst[n][K] ----------------
__global__ void __launch_bounds__(256) tp_pad_kernel(const float* __restrict__ src,
                                                     unsigned short* __restrict__ dst,
                                                     int srcld, int K, int nreal, int kreal) {
  int n = blockIdx.y;
  int k = blockIdx.x * 256 + threadIdx.x;
  if (k >= K) return;
  float v = (n < nreal && k < kreal) ? src[(size_t)k * srcld + n] : 0.f;
  dst[(size_t)n * K + k] = f2bf(v);
}

// ---------------- maa_w2 -> block-diagonal concat weight [10240][160] bf16 ----------------
__global__ void __launch_bounds__(256) w2cat_kernel(const float* __restrict__ w2,
                                                    unsigned short* __restrict__ dst) {
  int id = blockIdx.x * 256 + threadIdx.x;
  if (id >= 10240 * 160) return;
  int n = id / 160, kq = id - n * 160;
  int j = n >> 11, e = n & 2047;
  float v = ((kq >> 5) == j) ? w2[(size_t)kq * 2048 + e] : 0.f;
  dst[id] = f2bf(v);
}

// ---------------- LayerNorm over E per token ----------------
__global__ void __launch_bounds__(256) ln_kernel(const float* __restrict__ x,
                                                 const float* __restrict__ wt,
                                                 const float* __restrict__ bs,
                                                 float* __restrict__ out) {
  __shared__ float red[4];
  int tid = threadIdx.x;
  size_t base = (size_t)blockIdx.x * EE;
  int e = tid * 8;
  float4 v0 = *(const float4*)&x[base + e];
  float4 v1 = *(const float4*)&x[base + e + 4];
  float s = v0.x + v0.y + v0.z + v0.w + v1.x + v1.y + v1.z + v1.w;
#pragma unroll
  for (int off = 32; off >= 1; off >>= 1) s += __shfl_xor(s, off);
  if ((tid & 63) == 0) red[tid >> 6] = s;
  __syncthreads();
  float mean = (red[0] + red[1] + red[2] + red[3]) * (1.f / EE);
  __syncthreads();
  float d, q = 0.f;
  d = v0.x - mean; q += d * d; d = v0.y - mean; q += d * d;
  d = v0.z - mean; q += d * d; d = v0.w - mean; q += d * d;
  d = v1.x - mean; q += d * d; d = v1.y - mean; q += d * d;
  d = v1.z - mean; q += d * d; d = v1.w - mean; q += d * d;
#pragma unroll
  for (int off = 32; off >= 1; off >>= 1) q += __shfl_xor(q, off);
  if ((tid & 63) == 0) red[tid >> 6] = q;
  __syncthreads();
  float var = (red[0] + red[1] + red[2] + red[3]) * (1.f / EE);
  float rstd = rsqrtf(var + EPSF);
  float4 w0 = *(const float4*)&wt[e], w1 = *(const float4*)&wt[e + 4];
  float4 b0 = *(const float4*)&bs[e], b1 = *(const float4*)&bs[e + 4];
  float4 o0, o1;
  o0.x = (v0.x - mean) * rstd * w0.x + b0.x;
  o0.y = (v0.y - mean) * rstd * w0.y + b0.y;
  o0.z = (v0.z - mean) * rstd * w0.z + b0.z;
  o0.w = (v0.w - mean) * rstd * w0.w + b0.w;
  o1.x = (v1.x - mean) * rstd * w1.x + b1.x;
  o1.y = (v1.y - mean) * rstd * w1.y + b1.y;
  o1.z = (v1.z - mean) * rstd * w1.z + b1.z;
  o1.w = (v1.w - mean) * rstd * w1.w + b1.w;
  *(float4*)&out[base + e] = o0;
  *(float4*)&out[base + e + 4] = o1;
}

// ---------------- token-shift: xxm bf16 + sx f32 ----------------
__global__ void __launch_bounds__(256) shift_kernel(const float* __restrict__ xn,
                                                    const float* __restrict__ state,
                                                    const int* __restrict__ ip,
                                                    const float* __restrict__ maa_x,
                                                    unsigned short* __restrict__ xxm,
                                                    float* __restrict__ sx) {
  int tok = blockIdx.x;
  int b = tok >> 9, t = tok & 511;
  int tid = threadIdx.x;
  const float* cur = xn + (size_t)tok * EE;
  const float* prev = (t == 0)
      ? (state + ((size_t)b * (2 + SS) + (size_t)(2 + SS) * (*ip) + 1) * EE)
      : (cur - EE);
  int e = tid * 8;
#pragma unroll
  for (int half = 0; half < 2; ++half) {
    int eh = e + half * 4;
    float4 c = *(const float4*)&cur[eh];
    float4 p = *(const float4*)&prev[eh];
    float4 mx = *(const float4*)&maa_x[eh];
    float4 sv;
    sv.x = p.x - c.x; sv.y = p.y - c.y; sv.z = p.z - c.z; sv.w = p.w - c.w;
    *(float4*)&sx[(size_t)tok * EE + eh] = sv;
    ushort4 xo;
    xo.x = f2bf(c.x + sv.x * mx.x);
    xo.y = f2bf(c.y + sv.y * mx.y);
    xo.z = f2bf(c.z + sv.z * mx.z);
    xo.w = f2bf(c.w + sv.w * mx.w);
    *(ushort4*)&xxm[(size_t)tok * EE + eh] = xo;
  }
}

// ---------------- generic bf16 MFMA GEMM: C[m,n] = sum_k A[m,k]*W[n,k], M=2048 ----------------
// MODE 0: f32 acc. 1: f32 silu. 2: f32 addsrc+acc. 3: f32 addsrc+sigmoid(mulsrc)*acc.
// MODE 4: bf16 relu(acc)^2. 5: bf16 tanh(acc). 6: f32 exp(-exp(td[n]+acc)). 7: x5-assemble.
template <int MODE>
__global__ void __launch_bounds__(256) gemm_bt(const unsigned short* __restrict__ A, int lda,
                                               const unsigned short* __restrict__ W, int ldw,
                                               int K, int NB,
                                               void* __restrict__ Cout, int ldc,
                                               const float* __restrict__ p1,
                                               const float* __restrict__ p2,
                                               const float* __restrict__ p3) {
  __shared__ __align__(16) unsigned short As[128 * 32];
  __shared__ __align__(16) unsigned short Bs[128 * 32];
  int nwg = gridDim.x, bid = blockIdx.x;
  int qd = nwg >> 3;
  int wg = (bid & 7) * qd + (bid >> 3);  // bijective XCD swizzle (nwg % 8 == 0)
  int bm = wg / NB, bn = wg - bm * NB;
  int tid = threadIdx.x;
  int wave = tid >> 6, lane = tid & 63;
  int wm = wave >> 1, wn = wave & 1;
  f32x4 acc[4][4] = {};
  int srow = tid >> 2;
  int scol = (tid & 3) * 8;
  const unsigned short* Arow = A + (size_t)(bm * 128 + srow) * lda + scol;
  const unsigned short* Brow = W + (size_t)(bn * 128 + srow) * ldw + scol;
  const unsigned short* Arow2 = Arow + (size_t)64 * lda;
  const unsigned short* Brow2 = Brow + (size_t)64 * ldw;
  // LDS dest: As[srow*32+scol] = As[tid*8] -> byte offset tid*16: wave-uniform base + lane*16
  unsigned short* AsW = &As[tid * 8];
  unsigned short* AsW2 = &As[64 * 32 + tid * 8];
  unsigned short* BsW = &Bs[tid * 8];
  unsigned short* BsW2 = &Bs[64 * 32 + tid * 8];
  for (int k0 = 0; k0 < K; k0 += 32) {
    __syncthreads();  // prior iteration's ds_reads done before overwrite
    gload_lds16(Arow + k0, AsW);
    gload_lds16(Arow2 + k0, AsW2);
    gload_lds16(Brow + k0, BsW);
    gload_lds16(Brow2 + k0, BsW2);
    __syncthreads();  // drains vmcnt: LDS tile ready
    int kofs = (lane >> 4) * 8;
    int rA = wm * 64 + (lane & 15);
    int rB = wn * 64 + (lane & 15);
    short8 av[4], bv[4];
#pragma unroll
    for (int f = 0; f < 4; f++) {
      av[f] = *(const short8*)&As[(rA + f * 16) * 32 + kofs];
      bv[f] = *(const short8*)&Bs[(rB + f * 16) * 32 + kofs];
    }
#pragma unroll
    for (int fm = 0; fm < 4; fm++)
#pragma unroll
      for (int fn = 0; fn < 4; fn++)
        acc[fm][fn] = __builtin_amdgcn_mfma_f32_16x16x32_bf16(av[fm], bv[fn], acc[fm][fn], 0, 0, 0);
  }
  int m0 = bm * 128 + wm * 64;
  int n0 = bn * 128 + wn * 64;
  int rl = (lane >> 4) * 4;
  int cl = lane & 15;
#pragma unroll
  for (int fm = 0; fm < 4; fm++) {
#pragma unroll
    for (int fn = 0; fn < 4; fn++) {
#pragma unroll
      for (int q = 0; q < 4; q++) {
        int m = m0 + fm * 16 + rl + q;
        int n = n0 + fn * 16 + cl;
        size_t o = (size_t)m * ldc + n;
        float val = acc[fm][fn][q];
        if constexpr (MODE == 0) {
          ((float*)Cout)[o] = val;
        } else if constexpr (MODE == 1) {
          ((float*)Cout)[o] = val / (1.f + expf(-val));
        } else if constexpr (MODE == 2) {
          ((float*)Cout)[o] = p1[o] + val;
        } else if constexpr (MODE == 3) {
          ((float*)Cout)[o] = p1[o] + val * (1.f / (1.f + expf(-p2[o])));
        } else if constexpr (MODE == 4) {
          float rv = fmaxf(val, 0.f);
          ((unsigned short*)Cout)[o] = f2bf(rv * rv);
        } else if constexpr (MODE == 5) {
          ((unsigned short*)Cout)[o] = f2bf(tanhf(val));
        } else if constexpr (MODE == 6) {
          ((float*)Cout)[o] = expf(-expf(p1[n] + val));
        } else {  // MODE 7: x5 assemble: j = n>>11, e = n&2047
          int j = n >> 11, e = n & 2047;
          size_t oe = (size_t)m * EE + e;
          float xv = p1[oe];
          float sv = p2[oe];
          float st = p3[(size_t)j * EE + e];
          ((unsigned short*)Cout)[(size_t)j * NEL + oe] = f2bf(xv + sv * (st + val));
        }
      }
    }
  }
}

// ---------------- WKV scan v3: 8-step LDS group staging + deferred reduction ----------------
// block = 512 thr (8 waves) per (b,h); wave wv owns k-slice [wv*8, wv*8+8)
__global__ void __launch_bounds__(512) scan_kernel(const float* __restrict__ r,
                                                   const float* __restrict__ k,
                                                   const float* __restrict__ v,
                                                   const float* __restrict__ w,
                                                   const float* __restrict__ state,
                                                   const float* __restrict__ faaaa,
                                                   const int* __restrict__ ip,
                                                   float* __restrict__ att) {
  __shared__ float buf[2][4][8][64];  // [dbuf][r,k,v,w][t][d-or-k] = 16 KB
  __shared__ float part[8][8][64];    // [t][wv][d] = 16 KB
  int bh = blockIdx.x;
  int b = bh >> 5, h = bh & 31;
  int tid = threadIdx.x;
  int wv = tid >> 6, lane = tid & 63;
  int k0w = wv * 8;
  int ii = *ip;
  const float* sb = state + ((size_t)b * (2 + SS) + (size_t)(2 + SS) * ii + 2) * EE;
  float s_[8];
  {
    const float* p = sb + (size_t)(2 * h + (k0w >> 5)) * EE + (k0w & 31) * 64 + lane;
#pragma unroll
    for (int q = 0; q < 8; ++q) s_[q] = p[q * 64];
  }
  float u_[8];
#pragma unroll
  for (int q = 0; q < 8; ++q) u_[q] = faaaa[h * 64 + k0w + q];
  size_t base = (size_t)b * LL * EE + (size_t)h * 64;
  // cooperative loader mapping: tid -> array (0..3), t-row (0..7), 4-float chunk (0..15)
  int la = tid >> 7;
  int lt = (tid >> 4) & 7;
  int lc = (tid & 15) * 4;
  const float* arr = (la == 0) ? r : (la == 1) ? k : (la == 2) ? v : w;
  const float* lsrc = arr + base + (size_t)lt * EE + lc;
  *(float4*)&buf[0][la][lt][lc] = *(const float4*)lsrc;  // prologue group 0
  __syncthreads();
  for (int g = 0; g < 64; ++g) {
    int cb = g & 1;
    float4 nv;
    if (g < 63) nv = *(const float4*)(lsrc + (size_t)(g + 1) * 8 * EE);  // issue early
#pragma unroll
    for (int t = 0; t < 8; ++t) {
      float vv = buf[cb][2][t][lane];
      float acc = 0.f;
#pragma unroll
      for (int q = 0; q < 8; ++q) {
        float rk = buf[cb][0][t][k0w + q];  // wave-uniform -> LDS broadcast
        float kk = buf[cb][1][t][k0w + q];
        float wk = buf[cb][3][t][k0w + q];
        float a = kk * vv;
        acc = fmaf(rk, fmaf(u_[q], a, s_[q]), acc);
        s_[q] = fmaf(wk, s_[q], a);
      }
      part[t][wv][lane] = acc;
    }
    if (g < 63) *(float4*)&buf[cb ^ 1][la][lt][lc] = nv;  // write late (T14)
    __syncthreads();
    {
      int t = tid >> 6, d = tid & 63;
      float tot = part[t][0][d] + part[t][1][d] + part[t][2][d] + part[t][3][d] +
                  part[t][4][d] + part[t][5][d] + part[t][6][d] + part[t][7][d];
      att[base + (size_t)(g * 8 + t) * EE + d] = tot;
    }
    __syncthreads();
  }
}

// ---------------- GroupNorm (per head) + gate, out bf16 ----------------
__global__ void __launch_bounds__(256) gn_gate_kernel(const float* __restrict__ att,
                                                      const float* __restrict__ g,
                                                      const float* __restrict__ gnw,
                                                      const float* __restrict__ gnb,
                                                      unsigned short* __restrict__ attg) {
  int tok = blockIdx.x, tid = threadIdx.x;
  int h = tid >> 3, j = tid & 7;
  size_t base = (size_t)tok * EE + h * 64 + j * 8;
  int e = h * 64 + j * 8;
  float4 a0 = *(const float4*)&att[base];
  float4 a1 = *(const float4*)&att[base + 4];
  float s = a0.x + a0.y + a0.z + a0.w + a1.x + a1.y + a1.z + a1.w;
  s += __shfl_xor(s, 1); s += __shfl_xor(s, 2); s += __shfl_xor(s, 4);
  float mean = s * (1.f / 64.f);
  float d, q = 0.f;
  d = a0.x - mean; q += d * d; d = a0.y - mean; q += d * d;
  d = a0.z - mean; q += d * d; d = a0.w - mean; q += d * d;
  d = a1.x - mean; q += d * d; d = a1.y - mean; q += d * d;
  d = a1.z - mean; q += d * d; d = a1.w - mean; q += d * d;
  q += __shfl_xor(q, 1); q += __shfl_xor(q, 2); q += __shfl_xor(q, 4);
  float rstd = rsqrtf(q * (1.f / 64.f) + EPSF);
  float4 w0 = *(const float4*)&gnw[e], w1 = *(const float4*)&gnw[e + 4];
  float4 b0 = *(const float4*)&gnb[e], b1 = *(const float4*)&gnb[e + 4];
  float4 g0 = *(const float4*)&g[base], g1 = *(const float4*)&g[base + 4];
  ushort4 o0, o1;
  o0.x = f2bf(((a0.x - mean) * rstd * w0.x + b0.x) * g0.x);
  o0.y = f2bf(((a0.y - mean) * rstd * w0.y + b0.y) * g0.y);
  o0.z = f2bf(((a0.z - mean) * rstd * w0.z + b0.z) * g0.z);
  o0.w = f2bf(((a0.w - mean) * rstd * w0.w + b0.w) * g0.w);
  o1.x = f2bf(((a1.x - mean) * rstd * w1.x + b1.x) * g1.x);
  o1.y = f2bf(((a1.y - mean) * rstd * w1.y + b1.y) * g1.y);
  o1.z = f2bf(((a1.z - mean) * rstd * w1.z + b1.z) * g1.z);
  o1.w = f2bf(((a1.w - mean) * rstd * w1.w + b1.w) * g1.w);
  *(ushort4*)&attg[base] = o0;
  *(ushort4*)&attg[base + 4] = o1;
}

// ---------------- FFN token-shift, out bf16 xk/xr ----------------
__global__ void __launch_bounds__(256) ffn_shift_kernel(const float* __restrict__ xn2,
                                                        const float* __restrict__ state,
                                                        const int* __restrict__ ip,
                                                        const float* __restrict__ mk,
                                                        const float* __restrict__ mr,
                                                        unsigned short* __restrict__ xkb,
                                                        unsigned short* __restrict__ xrb) {
  size_t i4 = (size_t)blockIdx.x * 256 + threadIdx.x;
  size_t e0 = i4 * 4;
  if (e0 >= NEL) return;
  int tok = (int)(e0 >> 11);
  int c = (int)(e0 & 2047);
  int b = tok >> 9, t = tok & 511;
  float4 cur = *(const float4*)&xn2[e0];
  float4 prev;
  if (t == 0) {
    int ii = *ip;
    prev = *(const float4*)&state[((size_t)b * (2 + SS) + (size_t)(2 + SS) * ii + 0) * EE + c];
  } else {
    prev = *(const float4*)&xn2[e0 - EE];
  }
  float4 k4 = *(const float4*)&mk[c];
  float4 r4 = *(const float4*)&mr[c];
  ushort4 ko, ro;
  ko.x = f2bf(cur.x + (prev.x - cur.x) * k4.x);
  ko.y = f2bf(cur.y + (prev.y - cur.y) * k4.y);
  ko.z = f2bf(cur.z + (prev.z - cur.z) * k4.z);
  ko.w = f2bf(cur.w + (prev.w - cur.w) * k4.w);
  ro.x = f2bf(cur.x + (prev.x - cur.x) * r4.x);
  ro.y = f2bf(cur.y + (prev.y - cur.y) * r4.y);
  ro.z = f2bf(cur.z + (prev.z - cur.z) * r4.z);
  ro.w = f2bf(cur.w + (prev.w - cur.w) * r4.w);
  *(ushort4*)&xkb[e0] = ko;
  *(ushort4*)&xrb[e0] = ro;
}

extern "C" void kernel_launch(void* const* d_in, const int* in_sizes, int n_in,
                              void* d_out, int out_size, void* d_ws, size_t ws_size,
                              hipStream_t stream) {
  const float* x = (const float*)d_in[0];
  const float* state = (const float*)d_in[1];
  const float* ln1_w = (const float*)d_in[2];
  const float* ln1_b = (const float*)d_in[3];
  const float* ln2_w = (const float*)d_in[4];
  const float* ln2_b = (const float*)d_in[5];
  const float* maa_x = (const float*)d_in[6];
  const float* maa_w1 = (const float*)d_in[7];
  const float* maa_w2 = (const float*)d_in[8];
  const float* maa_stack = (const float*)d_in[9];
  const float* time_decay = (const float*)d_in[10];
  const float* decay_w1 = (const float*)d_in[11];
  const float* decay_w2 = (const float*)d_in[12];
  const float* faaaa = (const float*)d_in[13];
  const float* Wr = (const float*)d_in[14];
  const float* Wk = (const float*)d_in[15];
  const float* Wv = (const float*)d_in[16];
  const float* Wg = (const float*)d_in[17];
  const float* Wo = (const float*)d_in[18];
  const float* gn_w = (const float*)d_in[19];
  const float* gn_b = (const float*)d_in[20];
  const float* ffn_maa_k = (const float*)d_in[21];
  const float* ffn_maa_r = (const float*)d_in[22];
  const float* fWk = (const float*)d_in[23];
  const float* fWr = (const float*)d_in[24];
  const float* fWv = (const float*)d_in[25];
  const int* ip = (const int*)d_in[26];

  char* ws = (char*)d_ws;
  const size_t MB1 = 1024 * 1024;
  unsigned short* WB0 = (unsigned short*)ws;                       // 8 MB
  unsigned short* WB1 = (unsigned short*)(ws + 8 * MB1);           // 8 MB
  float* xn = (float*)(ws + 16 * MB1);                             // 16 MB (also att)
  unsigned short* x5b = (unsigned short*)(ws + 32 * MB1);          // 5 x 8 MB
  float* wbuf = (float*)(ws + 72 * MB1);                           // 16 MB (xxm in low 8)
  float* rbuf = (float*)(ws + 88 * MB1);                           // 16 MB
  float* kbuf = (float*)(ws + 104 * MB1);                          // 16 MB
  float* vbuf = (float*)(ws + 120 * MB1);                          // 16 MB
  float* gbuf = (float*)(ws + 136 * MB1);                          // 16 MB (sx first)
  char* smalls = ws + 152 * MB1;                                   // ~6.8 MB
  unsigned short* th = (unsigned short*)smalls;                    // 2048x256 = 1 MB
  unsigned short* w1T = (unsigned short*)(smalls + 1 * MB1);       // 256x2048 = 1 MB
  unsigned short* w2cat = (unsigned short*)(smalls + 2 * MB1);     // 10240x160 = 3.28 MB
  unsigned short* dw1T = (unsigned short*)(smalls + 5376 * 1024);  // 128x2048 = 0.5 MB
  unsigned short* dw2T = (unsigned short*)(smalls + 5888 * 1024);  // 2048x128 = 0.5 MB
  unsigned short* dt = (unsigned short*)(smalls + 6400 * 1024);    // 2048x128 = 0.5 MB

  unsigned short* xxm = (unsigned short*)wbuf;
  float* sx = gbuf;
  float* att = xn;
  unsigned short* attg = x5b;              // slot0
  float* xn2 = rbuf;
  unsigned short* xkb = x5b + 1 * NEL;     // slot1
  unsigned short* xrb = x5b + 2 * NEL;     // slot2
  unsigned short* kkb = x5b + 3 * NEL;     // slot3
  float* rrraw = wbuf;

  const int thr = 256;
  const int nconv = (int)(NEL / 4);

  // 1. LN1
  ln_kernel<<<BBATCH * LL, thr, 0, stream>>>(x, ln1_w, ln1_b, xn);
  // 2. token shift -> xxm bf16, sx f32
  shift_kernel<<<BBATCH * LL, thr, 0, stream>>>(xn, state, ip, maa_x, xxm, sx);
  // 3. weight preps
  tp_pad_kernel<<<dim3(8, 256), thr, 0, stream>>>(maa_w1, w1T, 160, 2048, 160, 2048);
  w2cat_kernel<<<6400, thr, 0, stream>>>(maa_w2, w2cat);
  tp_pad_kernel<<<dim3(8, 128), thr, 0, stream>>>(decay_w1, dw1T, 64, 2048, 64, 2048);
  tp_pad_kernel<<<dim3(1, 2048), thr, 0, stream>>>(decay_w2, dw2T, 2048, 128, 2048, 64);
  // 4. th = tanh(xxm @ w1T): N=256, grid 32
  gemm_bt<5><<<32, thr, 0, stream>>>(xxm, 2048, w1T, 2048, 2048, 2, th, 256, nullptr, nullptr, nullptr);
  // 5. x5 assemble GEMM: N=10240, K=160, grid 1280
  gemm_bt<7><<<1280, thr, 0, stream>>>(th, 256, w2cat, 160, 160, 80, x5b, 0, xn, sx, maa_stack);
  // 6. dt = tanh(x5_1 @ dw1T): N=128, grid 16
  gemm_bt<5><<<16, thr, 0, stream>>>(x5b + 1 * NEL, 2048, dw1T, 2048, 2048, 1, dt, 128, nullptr, nullptr, nullptr);
  // 7. w = exp(-exp(td + dt @ dw2T)): K=128, grid 256
  gemm_bt<6><<<256, thr, 0, stream>>>(dt, 128, dw2T, 128, 128, 16, wbuf, 2048, time_decay, nullptr, nullptr);
  // 8-11. k, v, r, g projections (weight conversion ping-pong)
  f2bf_kernel<<<4096, thr, 0, stream>>>(Wk, WB0, nconv);
  gemm_bt<0><<<256, thr, 0, stream>>>(x5b + 0 * NEL, 2048, WB0, 2048, 2048, 16, kbuf, 2048, nullptr, nullptr, nullptr);
  f2bf_kernel<<<4096, thr, 0, stream>>>(Wv, WB1, nconv);
  gemm_bt<0><<<256, thr, 0, stream>>>(x5b + 2 * NEL, 2048, WB1, 2048, 2048, 16, vbuf, 2048, nullptr, nullptr, nullptr);
  f2bf_kernel<<<4096, thr, 0, stream>>>(Wr, WB0, nconv);
  gemm_bt<0><<<256, thr, 0, stream>>>(x5b + 3 * NEL, 2048, WB0, 2048, 2048, 16, rbuf, 2048, nullptr, nullptr, nullptr);
  f2bf_kernel<<<4096, thr, 0, stream>>>(Wg, WB1, nconv);
  gemm_bt<1><<<256, thr, 0, stream>>>(x5b + 4 * NEL, 2048, WB1, 2048, 2048, 16, gbuf, 2048, nullptr, nullptr, nullptr);
  // 12. scan
  scan_kernel<<<BBATCH * HH, 512, 0, stream>>>(rbuf, kbuf, vbuf, wbuf, state, faaaa, ip, att);
  // 13. groupnorm + gate
  gn_gate_kernel<<<BBATCH * LL, thr, 0, stream>>>(att, gbuf, gn_w, gn_b, attg);
  // 14. out = x + attg @ Wo^T
  f2bf_kernel<<<4096, thr, 0, stream>>>(Wo, WB0, nconv);
  gemm_bt<2><<<256, thr, 0, stream>>>(attg, 2048, WB0, 2048, 2048, 16, (float*)d_out, 2048, x, nullptr, nullptr);
  // 15. LN2
  ln_kernel<<<BBATCH * LL, thr, 0, stream>>>((const float*)d_out, ln2_w, ln2_b, xn2);
  // 16. FFN shift
  ffn_shift_kernel<<<4096, thr, 0, stream>>>(xn2, state, ip, ffn_maa_k, ffn_maa_r, xkb, xrb);
  // 17. rr raw logits
  f2bf_kernel<<<4096, thr, 0, stream>>>(fWr, WB1, nconv);
  gemm_bt<0><<<256, thr, 0, stream>>>(xrb, 2048, WB1, 2048, 2048, 16, rrraw, 2048, nullptr, nullptr, nullptr);
  // 18. kk = relu(xk @ fWk^T)^2 -> bf16
  f2bf_kernel<<<4096, thr, 0, stream>>>(fWk, WB0, nconv);
  gemm_bt<4><<<256, thr, 0, stream>>>(xkb, 2048, WB0, 2048, 2048, 16, kkb, 2048, nullptr, nullptr, nullptr);
  // 19. out += sigmoid(rr) * (kk @ fWv^T)
  f2bf_kernel<<<4096, thr, 0, stream>>>(fWv, WB1, nconv);
  gemm_bt<3><<<256, thr, 0, stream>>>(kkb, 2048, WB1, 2048, 2048, 16, (float*)d_out, 2048, (const float*)d_out, rrraw, nullptr);
}

// Round 6
// 556.584 us; speedup vs baseline: 3.4304x; 1.3323x over previous
//
#include <hip/hip_runtime.h>

#define EE 2048
#define LL 512
#define BBATCH 4
#define HH 32
#define SS 64
#define EPSF 1e-5f
static constexpr size_t NEL = (size_t)BBATCH * LL * EE;  // 4,194,304

typedef __attribute__((ext_vector_type(8))) short short8;
typedef __attribute__((ext_vector_type(4))) float f32x4;

__device__ __forceinline__ unsigned short f2bf(float f) {
  union { float f; unsigned u; } x; x.f = f;
  return (unsigned short)((x.u + 0x7fffu + ((x.u >> 16) & 1u)) >> 16);
}

__device__ __forceinline__ void gload_lds16(const unsigned short* g, unsigned short* l) {
  __builtin_amdgcn_global_load_lds((const __attribute__((address_space(1))) void*)g,
                                   (__attribute__((address_space(3))) void*)l, 16, 0, 0);
}

// ---------------- fp32 -> bf16 conversion ----------------
__global__ void __launch_bounds__(256) f2bf_kernel(const float* __restrict__ src,
                                                   unsigned short* __restrict__ dst, int n4) {
  int idx = blockIdx.x * 256 + threadIdx.x;
  if (idx >= n4) return;
  float4 v = ((const float4*)src)[idx];
  ushort4 o;
  o.x = f2bf(v.x); o.y = f2bf(v.y); o.z = f2bf(v.z); o.w = f2bf(v.w);
  ((ushort4*)dst)[idx] = o;
}

// ---------------- transpose + zero-pad, f32 src -> bf16 dst[n][K] ----------------
__global__ void __launch_bounds__(256) tp_pad_kernel(const float* __restrict__ src,
                                                     unsigned short* __restrict__ dst,
                                                     int srcld, int K, int nreal, int kreal) {
  int n = blockIdx.y;
  int k = blockIdx.x * 256 + threadIdx.x;
  if (k >= K) return;
  float v = (n < nreal && k < kreal) ? src[(size_t)k * srcld + n] : 0.f;
  dst[(size_t)n * K + k] = f2bf(v);
}

// ---------------- maa_w2 -> block-diagonal concat weight [10240][160] bf16 ----------------
__global__ void __launch_bounds__(256) w2cat_kernel(const float* __restrict__ w2,
                                                    unsigned short* __restrict__ dst) {
  int id = blockIdx.x * 256 + threadIdx.x;
  if (id >= 10240 * 160) return;
  int n = id / 160, kq = id - n * 160;
  int j = n >> 11, e = n & 2047;
  float v = ((kq >> 5) == j) ? w2[(size_t)kq * 2048 + e] : 0.f;
  dst[id] = f2bf(v);
}

// ---------------- LayerNorm over E per token ----------------
__global__ void __launch_bounds__(256) ln_kernel(const float* __restrict__ x,
                                                 const float* __restrict__ wt,
                                                 const float* __restrict__ bs,
                                                 float* __restrict__ out) {
  __shared__ float red[4];
  int tid = threadIdx.x;
  size_t base = (size_t)blockIdx.x * EE;
  int e = tid * 8;
  float4 v0 = *(const float4*)&x[base + e];
  float4 v1 = *(const float4*)&x[base + e + 4];
  float s = v0.x + v0.y + v0.z + v0.w + v1.x + v1.y + v1.z + v1.w;
#pragma unroll
  for (int off = 32; off >= 1; off >>= 1) s += __shfl_xor(s, off);
  if ((tid & 63) == 0) red[tid >> 6] = s;
  __syncthreads();
  float mean = (red[0] + red[1] + red[2] + red[3]) * (1.f / EE);
  __syncthreads();
  float d, q = 0.f;
  d = v0.x - mean; q += d * d; d = v0.y - mean; q += d * d;
  d = v0.z - mean; q += d * d; d = v0.w - mean; q += d * d;
  d = v1.x - mean; q += d * d; d = v1.y - mean; q += d * d;
  d = v1.z - mean; q += d * d; d = v1.w - mean; q += d * d;
#pragma unroll
  for (int off = 32; off >= 1; off >>= 1) q += __shfl_xor(q, off);
  if ((tid & 63) == 0) red[tid >> 6] = q;
  __syncthreads();
  float var = (red[0] + red[1] + red[2] + red[3]) * (1.f / EE);
  float rstd = rsqrtf(var + EPSF);
  float4 w0 = *(const float4*)&wt[e], w1 = *(const float4*)&wt[e + 4];
  float4 b0 = *(const float4*)&bs[e], b1 = *(const float4*)&bs[e + 4];
  float4 o0, o1;
  o0.x = (v0.x - mean) * rstd * w0.x + b0.x;
  o0.y = (v0.y - mean) * rstd * w0.y + b0.y;
  o0.z = (v0.z - mean) * rstd * w0.z + b0.z;
  o0.w = (v0.w - mean) * rstd * w0.w + b0.w;
  o1.x = (v1.x - mean) * rstd * w1.x + b1.x;
  o1.y = (v1.y - mean) * rstd * w1.y + b1.y;
  o1.z = (v1.z - mean) * rstd * w1.z + b1.z;
  o1.w = (v1.w - mean) * rstd * w1.w + b1.w;
  *(float4*)&out[base + e] = o0;
  *(float4*)&out[base + e + 4] = o1;
}

// ---------------- token-shift: xxm bf16 + sx f32 ----------------
__global__ void __launch_bounds__(256) shift_kernel(const float* __restrict__ xn,
                                                    const float* __restrict__ state,
                                                    const int* __restrict__ ip,
                                                    const float* __restrict__ maa_x,
                                                    unsigned short* __restrict__ xxm,
                                                    float* __restrict__ sx) {
  int tok = blockIdx.x;
  int b = tok >> 9, t = tok & 511;
  int tid = threadIdx.x;
  const float* cur = xn + (size_t)tok * EE;
  const float* prev = (t == 0)
      ? (state + ((size_t)b * (2 + SS) + (size_t)(2 + SS) * (*ip) + 1) * EE)
      : (cur - EE);
  int e = tid * 8;
#pragma unroll
  for (int half = 0; half < 2; ++half) {
    int eh = e + half * 4;
    float4 c = *(const float4*)&cur[eh];
    float4 p = *(const float4*)&prev[eh];
    float4 mx = *(const float4*)&maa_x[eh];
    float4 sv;
    sv.x = p.x - c.x; sv.y = p.y - c.y; sv.z = p.z - c.z; sv.w = p.w - c.w;
    *(float4*)&sx[(size_t)tok * EE + eh] = sv;
    ushort4 xo;
    xo.x = f2bf(c.x + sv.x * mx.x);
    xo.y = f2bf(c.y + sv.y * mx.y);
    xo.z = f2bf(c.z + sv.z * mx.z);
    xo.w = f2bf(c.w + sv.w * mx.w);
    *(ushort4*)&xxm[(size_t)tok * EE + eh] = xo;
  }
}

// ---------------- GEMM core: C_tile = A[m,:K] x W[n,:K]^T (both row-major [*,K]) ----------------
// 256 threads, 4 waves as 2x2. Per-wave tile (BM/2)x(BN/2). gload_lds staging, BK=32.
template <int BM, int BN>
__device__ __forceinline__ void gemm_core(const unsigned short* __restrict__ A, int lda,
                                          const unsigned short* __restrict__ W, int ldw,
                                          int K, int NB, unsigned short* As, unsigned short* Bs,
                                          f32x4 (&acc)[BM / 32][BN / 32], int& m0o, int& n0o) {
  constexpr int FM = BM / 32, FN = BN / 32, RA = BM / 64, RB = BN / 64;
  int nwg = gridDim.x, bid = blockIdx.x;
  int qd = nwg >> 3;
  int wg = (bid & 7) * qd + (bid >> 3);  // bijective XCD swizzle (nwg % 8 == 0)
  int bm = wg / NB, bn = wg - bm * NB;
  int tid = threadIdx.x;
  int wave = tid >> 6, lane = tid & 63;
  int wm = wave >> 1, wn = wave & 1;
  int srow = tid >> 2, scol = (tid & 3) * 8;
  const unsigned short* Arow = A + (size_t)(bm * BM + srow) * lda + scol;
  const unsigned short* Brow = W + (size_t)(bn * BN + srow) * ldw + scol;
  for (int k0 = 0; k0 < K; k0 += 32) {
    __syncthreads();  // prior ds_reads done before overwrite
#pragma unroll
    for (int rr_ = 0; rr_ < RA; ++rr_)
      gload_lds16(Arow + (size_t)(64 * rr_) * lda + k0, &As[64 * rr_ * 32 + tid * 8]);
#pragma unroll
    for (int rr_ = 0; rr_ < RB; ++rr_)
      gload_lds16(Brow + (size_t)(64 * rr_) * ldw + k0, &Bs[64 * rr_ * 32 + tid * 8]);
    __syncthreads();  // drains vmcnt: LDS tile ready
    int kofs = (lane >> 4) * 8;
    int rA = wm * (BM / 2) + (lane & 15);
    int rB = wn * (BN / 2) + (lane & 15);
    short8 av[FM], bv[FN];
#pragma unroll
    for (int f = 0; f < FM; f++) av[f] = *(const short8*)&As[(rA + f * 16) * 32 + kofs];
#pragma unroll
    for (int f = 0; f < FN; f++) bv[f] = *(const short8*)&Bs[(rB + f * 16) * 32 + kofs];
#pragma unroll
    for (int fm = 0; fm < FM; fm++)
#pragma unroll
      for (int fn = 0; fn < FN; fn++)
        acc[fm][fn] = __builtin_amdgcn_mfma_f32_16x16x32_bf16(av[fm], bv[fn], acc[fm][fn], 0, 0, 0);
  }
  m0o = bm * BM + wm * (BM / 2);
  n0o = bn * BN + wn * (BN / 2);
}

// epilogue: functor f(m, n, val) called for each element this thread owns
template <int FM, int FN, typename F>
__device__ __forceinline__ void epi_loop(f32x4 (&acc)[FM][FN], int m0, int n0, F f) {
  int lane = threadIdx.x & 63;
  int rl = (lane >> 4) * 4, cl = lane & 15;
#pragma unroll
  for (int fm = 0; fm < FM; fm++)
#pragma unroll
    for (int fn = 0; fn < FN; fn++)
#pragma unroll
      for (int q = 0; q < 4; q++)
        f(m0 + fm * 16 + rl + q, n0 + fn * 16 + cl, acc[fm][fn][q]);
}

// MODE 2: f32 p1+acc. 3: f32 p1+sigmoid(p2)*acc. 5: bf16 tanh. 6: f32 exp(-exp(p1[n]+acc)). 7: x5.
template <int MODE, int BM, int BN>
__global__ void __launch_bounds__(256) gemm_bt(const unsigned short* __restrict__ A, int lda,
                                               const unsigned short* __restrict__ W, int ldw,
                                               int K, int NB, void* __restrict__ Cout, int ldc,
                                               const float* __restrict__ p1,
                                               const float* __restrict__ p2,
                                               const float* __restrict__ p3) {
  __shared__ __align__(16) unsigned short As[BM * 32];
  __shared__ __align__(16) unsigned short Bs[BN * 32];
  f32x4 acc[BM / 32][BN / 32] = {};
  int m0, n0;
  gemm_core<BM, BN>(A, lda, W, ldw, K, NB, As, Bs, acc, m0, n0);
  epi_loop(acc, m0, n0, [&](int m, int n, float val) {
    size_t o = (size_t)m * ldc + n;
    if constexpr (MODE == 2) {
      ((float*)Cout)[o] = p1[o] + val;
    } else if constexpr (MODE == 3) {
      ((float*)Cout)[o] = p1[o] + val * (1.f / (1.f + expf(-p2[o])));
    } else if constexpr (MODE == 5) {
      ((unsigned short*)Cout)[o] = f2bf(tanhf(val));
    } else if constexpr (MODE == 6) {
      ((float*)Cout)[o] = expf(-expf(p1[n] + val));
    } else {  // MODE 7: x5 assemble: j = n>>11, e = n&2047
      int j = n >> 11, e = n & 2047;
      size_t oe = (size_t)m * EE + e;
      float xv = p1[oe];
      float sv = p2[oe];
      float st = p3[(size_t)j * EE + e];
      ((unsigned short*)Cout)[(size_t)j * NEL + oe] = f2bf(xv + sv * (st + val));
    }
  });
}

// ---- batched 4-GEMM (k,v,r,g projections); z = blockIdx.y; z==3 -> silu ----
struct Proj4Args {
  const unsigned short* A[4];
  const unsigned short* W[4];
  float* C[4];
};
__global__ void __launch_bounds__(256) gemm_proj4(Proj4Args args) {
  __shared__ __align__(16) unsigned short As[128 * 32];
  __shared__ __align__(16) unsigned short Bs[128 * 32];
  int z = blockIdx.y;
  f32x4 acc[4][4] = {};
  int m0, n0;
  gemm_core<128, 128>(args.A[z], EE, args.W[z], EE, EE, 16, As, Bs, acc, m0, n0);
  float* C = args.C[z];
  bool silu = (z == 3);
  epi_loop(acc, m0, n0, [&](int m, int n, float val) {
    size_t o = (size_t)m * EE + n;
    C[o] = silu ? (val / (1.f + expf(-val))) : val;
  });
}

// ---- batched 2-GEMM (rr f32 ; kk = relu^2 bf16); z = blockIdx.y ----
__global__ void __launch_bounds__(256) gemm_ffn2(const unsigned short* A0,
                                                 const unsigned short* A1,
                                                 const unsigned short* W0,
                                                 const unsigned short* W1, float* C0,
                                                 unsigned short* C1) {
  __shared__ __align__(16) unsigned short As[128 * 32];
  __shared__ __align__(16) unsigned short Bs[128 * 32];
  int z = blockIdx.y;
  f32x4 acc[4][4] = {};
  int m0, n0;
  gemm_core<128, 128>(z ? A1 : A0, EE, z ? W1 : W0, EE, EE, 16, As, Bs, acc, m0, n0);
  epi_loop(acc, m0, n0, [&](int m, int n, float val) {
    size_t o = (size_t)m * EE + n;
    if (z == 0) {
      C0[o] = val;
    } else {
      float rv = fmaxf(val, 0.f);
      C1[o] = f2bf(rv * rv);
    }
  });
}

// ---------------- WKV scan v5: 2 blocks per head (k-split), atomicAdd combine ----------------
// 256 blocks x 512 thr. Block = (bh, khalf). 8 waves x 4 k-slots; lane = d.
__global__ void __launch_bounds__(512) scan_kernel(const float* __restrict__ r,
                                                   const float* __restrict__ k,
                                                   const float* __restrict__ v,
                                                   const float* __restrict__ w,
                                                   const float* __restrict__ state,
                                                   const float* __restrict__ faaaa,
                                                   const int* __restrict__ ip,
                                                   float* __restrict__ att) {
  __shared__ float bR[2][8][32], bK[2][8][32], bW[2][8][32];  // k-half rows
  __shared__ float bV[2][8][64];
  __shared__ float part[8][8][64];  // [t][wave][d]
  int blk = blockIdx.x;
  int bh = blk >> 1, kh = blk & 1;
  int b = bh >> 5, h = bh & 31;
  int tid = threadIdx.x, wv = tid >> 6, lane = tid & 63;
  int klocal = wv * 4;
  int k0w = kh * 32 + klocal;
  int ii = *ip;
  const float* sb = state + ((size_t)b * (2 + SS) + (size_t)(2 + SS) * ii + 2) * EE;
  float s_[4], u_[4];
#pragma unroll
  for (int q = 0; q < 4; ++q) {
    int kk_ = k0w + q;
    s_[q] = sb[(size_t)(2 * h + (kk_ >> 5)) * EE + (kk_ & 31) * 64 + lane];
    u_[q] = faaaa[h * 64 + kk_];
  }
  size_t base = (size_t)b * LL * EE + (size_t)h * 64;
  // loader: 320 active threads, 1 float4/group each
  int c = tid;
  bool ld = c < 320;
  int lt = c / 40, r40 = c - lt * 40;
  int la = (r40 < 24) ? (r40 >> 3) : 3;  // 0=r 1=k 2=w 3=v
  int lcG = (r40 < 24) ? (kh * 32 + (r40 & 7) * 4) : ((r40 - 24) * 4);
  int lcL = (r40 < 24) ? ((r40 & 7) * 4) : ((r40 - 24) * 4);
  const float* lsrc = nullptr;
  if (ld) {
    const float* arr = (la == 0) ? r : (la == 1) ? k : (la == 2) ? w : v;
    lsrc = arr + base + (size_t)lt * EE + lcG;
    float4 v0 = *(const float4*)lsrc;
    if (la == 0) *(float4*)&bR[0][lt][lcL] = v0;
    else if (la == 1) *(float4*)&bK[0][lt][lcL] = v0;
    else if (la == 2) *(float4*)&bW[0][lt][lcL] = v0;
    else *(float4*)&bV[0][lt][lcL] = v0;
  }
  __syncthreads();
  for (int g = 0; g < 64; ++g) {
    int cb = g & 1;
    float4 nv;
    if (ld && g < 63) nv = *(const float4*)(lsrc + (size_t)(g + 1) * 8 * EE);
#pragma unroll
    for (int t = 0; t < 8; ++t) {
      float vv = bV[cb][t][lane];
      float acc = 0.f;
#pragma unroll
      for (int q = 0; q < 4; ++q) {
        float rk = bR[cb][t][klocal + q];  // wave-uniform -> broadcast
        float kk2 = bK[cb][t][klocal + q];
        float wk = bW[cb][t][klocal + q];
        float a = kk2 * vv;
        acc = fmaf(rk, fmaf(u_[q], a, s_[q]), acc);
        s_[q] = fmaf(wk, s_[q], a);
      }
      part[t][wv][lane] = acc;
    }
    if (ld && g < 63) {
      int nb = cb ^ 1;
      if (la == 0) *(float4*)&bR[nb][lt][lcL] = nv;
      else if (la == 1) *(float4*)&bK[nb][lt][lcL] = nv;
      else if (la == 2) *(float4*)&bW[nb][lt][lcL] = nv;
      else *(float4*)&bV[nb][lt][lcL] = nv;
    }
    __syncthreads();
    {
      int t = tid >> 6, d = tid & 63;
      float tot = part[t][0][d] + part[t][1][d] + part[t][2][d] + part[t][3][d] +
                  part[t][4][d] + part[t][5][d] + part[t][6][d] + part[t][7][d];
      atomicAdd(&att[base + (size_t)(g * 8 + t) * EE + d], tot);
    }
    __syncthreads();
  }
}

// ---------------- GroupNorm (per head) + gate, out bf16 ----------------
__global__ void __launch_bounds__(256) gn_gate_kernel(const float* __restrict__ att,
                                                      const float* __restrict__ g,
                                                      const float* __restrict__ gnw,
                                                      const float* __restrict__ gnb,
                                                      unsigned short* __restrict__ attg) {
  int tok = blockIdx.x, tid = threadIdx.x;
  int h = tid >> 3, j = tid & 7;
  size_t base = (size_t)tok * EE + h * 64 + j * 8;
  int e = h * 64 + j * 8;
  float4 a0 = *(const float4*)&att[base];
  float4 a1 = *(const float4*)&att[base + 4];
  float s = a0.x + a0.y + a0.z + a0.w + a1.x + a1.y + a1.z + a1.w;
  s += __shfl_xor(s, 1); s += __shfl_xor(s, 2); s += __shfl_xor(s, 4);
  float mean = s * (1.f / 64.f);
  float d, q = 0.f;
  d = a0.x - mean; q += d * d; d = a0.y - mean; q += d * d;
  d = a0.z - mean; q += d * d; d = a0.w - mean; q += d * d;
  d = a1.x - mean; q += d * d; d = a1.y - mean; q += d * d;
  d = a1.z - mean; q += d * d; d = a1.w - mean; q += d * d;
  q += __shfl_xor(q, 1); q += __shfl_xor(q, 2); q += __shfl_xor(q, 4);
  float rstd = rsqrtf(q * (1.f / 64.f) + EPSF);
  float4 w0 = *(const float4*)&gnw[e], w1 = *(const float4*)&gnw[e + 4];
  float4 b0 = *(const float4*)&gnb[e], b1 = *(const float4*)&gnb[e + 4];
  float4 g0 = *(const float4*)&g[base], g1 = *(const float4*)&g[base + 4];
  ushort4 o0, o1;
  o0.x = f2bf(((a0.x - mean) * rstd * w0.x + b0.x) * g0.x);
  o0.y = f2bf(((a0.y - mean) * rstd * w0.y + b0.y) * g0.y);
  o0.z = f2bf(((a0.z - mean) * rstd * w0.z + b0.z) * g0.z);
  o0.w = f2bf(((a0.w - mean) * rstd * w0.w + b0.w) * g0.w);
  o1.x = f2bf(((a1.x - mean) * rstd * w1.x + b1.x) * g1.x);
  o1.y = f2bf(((a1.y - mean) * rstd * w1.y + b1.y) * g1.y);
  o1.z = f2bf(((a1.z - mean) * rstd * w1.z + b1.z) * g1.z);
  o1.w = f2bf(((a1.w - mean) * rstd * w1.w + b1.w) * g1.w);
  *(ushort4*)&attg[base] = o0;
  *(ushort4*)&attg[base + 4] = o1;
}

// ---------------- FFN token-shift, out bf16 xk/xr ----------------
__global__ void __launch_bounds__(256) ffn_shift_kernel(const float* __restrict__ xn2,
                                                        const float* __restrict__ state,
                                                        const int* __restrict__ ip,
                                                        const float* __restrict__ mk,
                                                        const float* __restrict__ mr,
                                                        unsigned short* __restrict__ xkb,
                                                        unsigned short* __restrict__ xrb) {
  size_t i4 = (size_t)blockIdx.x * 256 + threadIdx.x;
  size_t e0 = i4 * 4;
  if (e0 >= NEL) return;
  int tok = (int)(e0 >> 11);
  int c = (int)(e0 & 2047);
  int b = tok >> 9, t = tok & 511;
  float4 cur = *(const float4*)&xn2[e0];
  float4 prev;
  if (t == 0) {
    int ii = *ip;
    prev = *(const float4*)&state[((size_t)b * (2 + SS) + (size_t)(2 + SS) * ii + 0) * EE + c];
  } else {
    prev = *(const float4*)&xn2[e0 - EE];
  }
  float4 k4 = *(const float4*)&mk[c];
  float4 r4 = *(const float4*)&mr[c];
  ushort4 ko, ro;
  ko.x = f2bf(cur.x + (prev.x - cur.x) * k4.x);
  ko.y = f2bf(cur.y + (prev.y - cur.y) * k4.y);
  ko.z = f2bf(cur.z + (prev.z - cur.z) * k4.z);
  ko.w = f2bf(cur.w + (prev.w - cur.w) * k4.w);
  ro.x = f2bf(cur.x + (prev.x - cur.x) * r4.x);
  ro.y = f2bf(cur.y + (prev.y - cur.y) * r4.y);
  ro.z = f2bf(cur.z + (prev.z - cur.z) * r4.z);
  ro.w = f2bf(cur.w + (prev.w - cur.w) * r4.w);
  *(ushort4*)&xkb[e0] = ko;
  *(ushort4*)&xrb[e0] = ro;
}

extern "C" void kernel_launch(void* const* d_in, const int* in_sizes, int n_in,
                              void* d_out, int out_size, void* d_ws, size_t ws_size,
                              hipStream_t stream) {
  const float* x = (const float*)d_in[0];
  const float* state = (const float*)d_in[1];
  const float* ln1_w = (const float*)d_in[2];
  const float* ln1_b = (const float*)d_in[3];
  const float* ln2_w = (const float*)d_in[4];
  const float* ln2_b = (const float*)d_in[5];
  const float* maa_x = (const float*)d_in[6];
  const float* maa_w1 = (const float*)d_in[7];
  const float* maa_w2 = (const float*)d_in[8];
  const float* maa_stack = (const float*)d_in[9];
  const float* time_decay = (const float*)d_in[10];
  const float* decay_w1 = (const float*)d_in[11];
  const float* decay_w2 = (const float*)d_in[12];
  const float* faaaa = (const float*)d_in[13];
  const float* Wr = (const float*)d_in[14];
  const float* Wk = (const float*)d_in[15];
  const float* Wv = (const float*)d_in[16];
  const float* Wg = (const float*)d_in[17];
  const float* Wo = (const float*)d_in[18];
  const float* gn_w = (const float*)d_in[19];
  const float* gn_b = (const float*)d_in[20];
  const float* ffn_maa_k = (const float*)d_in[21];
  const float* ffn_maa_r = (const float*)d_in[22];
  const float* fWk = (const float*)d_in[23];
  const float* fWr = (const float*)d_in[24];
  const float* fWv = (const float*)d_in[25];
  const int* ip = (const int*)d_in[26];

  char* ws = (char*)d_ws;
  const size_t MB1 = 1024 * 1024;
  unsigned short* WB0 = (unsigned short*)ws;                       // 8 MB
  unsigned short* WB1 = (unsigned short*)(ws + 8 * MB1);           // 8 MB
  float* xn = (float*)(ws + 16 * MB1);                             // 16 MB (also WB2/WB3, att)
  unsigned short* x5b = (unsigned short*)(ws + 32 * MB1);          // 5 x 8 MB
  float* wbuf = (float*)(ws + 72 * MB1);                           // 16 MB (xxm in low 8)
  float* rbuf = (float*)(ws + 88 * MB1);                           // 16 MB
  float* kbuf = (float*)(ws + 104 * MB1);                          // 16 MB
  float* vbuf = (float*)(ws + 120 * MB1);                          // 16 MB
  float* gbuf = (float*)(ws + 136 * MB1);                          // 16 MB (sx first)
  char* smalls = ws + 152 * MB1;                                   // ~6.8 MB
  unsigned short* th = (unsigned short*)smalls;                    // 1 MB
  unsigned short* w1T = (unsigned short*)(smalls + 1 * MB1);       // 1 MB
  unsigned short* w2cat = (unsigned short*)(smalls + 2 * MB1);     // 3.28 MB
  unsigned short* dw1T = (unsigned short*)(smalls + 5376 * 1024);  // 0.5 MB
  unsigned short* dw2T = (unsigned short*)(smalls + 5888 * 1024);  // 0.5 MB
  unsigned short* dt = (unsigned short*)(smalls + 6400 * 1024);    // 0.5 MB

  unsigned short* xxm = (unsigned short*)wbuf;
  float* sx = gbuf;
  float* att = xn;
  unsigned short* WB2 = (unsigned short*)xn;   // xn dead after x5 assemble
  unsigned short* WB3 = WB2 + NEL;
  unsigned short* attg = x5b;              // slot0
  float* xn2 = rbuf;
  unsigned short* xkb = x5b + 1 * NEL;     // slot1
  unsigned short* xrb = x5b + 2 * NEL;     // slot2
  unsigned short* kkb = x5b + 3 * NEL;     // slot3
  float* rrraw = wbuf;

  const int thr = 256;
  const int nconv = (int)(NEL / 4);

  // 1. LN1
  ln_kernel<<<BBATCH * LL, thr, 0, stream>>>(x, ln1_w, ln1_b, xn);
  // 2. token shift
  shift_kernel<<<BBATCH * LL, thr, 0, stream>>>(xn, state, ip, maa_x, xxm, sx);
  // 3. weight preps
  tp_pad_kernel<<<dim3(8, 256), thr, 0, stream>>>(maa_w1, w1T, 160, 2048, 160, 2048);
  w2cat_kernel<<<6400, thr, 0, stream>>>(maa_w2, w2cat);
  tp_pad_kernel<<<dim3(8, 128), thr, 0, stream>>>(decay_w1, dw1T, 64, 2048, 64, 2048);
  tp_pad_kernel<<<dim3(1, 2048), thr, 0, stream>>>(decay_w2, dw2T, 2048, 128, 2048, 64);
  // 4. th = tanh(xxm @ w1T): 64x64 tiles, grid 32*4=128
  gemm_bt<5, 64, 64><<<128, thr, 0, stream>>>(xxm, 2048, w1T, 2048, 2048, 4, th, 256,
                                              nullptr, nullptr, nullptr);
  // 5. x5 assemble: N=10240, K=160, grid 1280
  gemm_bt<7, 128, 128><<<1280, thr, 0, stream>>>(th, 256, w2cat, 160, 160, 80, x5b, 0,
                                                 xn, sx, maa_stack);
  // 6. dt = tanh(x5_1 @ dw1T): 64x64 tiles, grid 32*2=64
  gemm_bt<5, 64, 64><<<64, thr, 0, stream>>>(x5b + 1 * NEL, 2048, dw1T, 2048, 2048, 2, dt, 128,
                                             nullptr, nullptr, nullptr);
  // 7. w = exp(-exp(td + dt @ dw2T)): K=128
  gemm_bt<6, 128, 128><<<256, thr, 0, stream>>>(dt, 128, dw2T, 128, 128, 16, wbuf, 2048,
                                                time_decay, nullptr, nullptr);
  // 8. convert 4 projection weights (WB2/WB3 overlay dead xn)
  f2bf_kernel<<<4096, thr, 0, stream>>>(Wk, WB0, nconv);
  f2bf_kernel<<<4096, thr, 0, stream>>>(Wv, WB1, nconv);
  f2bf_kernel<<<4096, thr, 0, stream>>>(Wr, WB2, nconv);
  f2bf_kernel<<<4096, thr, 0, stream>>>(Wg, WB3, nconv);
  // 9. batched k,v,r,g projections: grid (256,4) = 1024 WGs
  {
    Proj4Args pa;
    pa.A[0] = x5b + 0 * NEL; pa.W[0] = WB0; pa.C[0] = kbuf;
    pa.A[1] = x5b + 2 * NEL; pa.W[1] = WB1; pa.C[1] = vbuf;
    pa.A[2] = x5b + 3 * NEL; pa.W[2] = WB2; pa.C[2] = rbuf;
    pa.A[3] = x5b + 4 * NEL; pa.W[3] = WB3; pa.C[3] = gbuf;
    gemm_proj4<<<dim3(256, 4), thr, 0, stream>>>(pa);
  }
  // 10. scan (atomicAdd combine -> zero att first)
  (void)hipMemsetAsync(att, 0, NEL * sizeof(float), stream);
  scan_kernel<<<256, 512, 0, stream>>>(rbuf, kbuf, vbuf, wbuf, state, faaaa, ip, att);
  // 11. groupnorm + gate
  gn_gate_kernel<<<BBATCH * LL, thr, 0, stream>>>(att, gbuf, gn_w, gn_b, attg);
  // 12. out = x + attg @ Wo^T : 128x64 tiles, grid 512
  f2bf_kernel<<<4096, thr, 0, stream>>>(Wo, WB0, nconv);
  gemm_bt<2, 128, 64><<<512, thr, 0, stream>>>(attg, 2048, WB0, 2048, 2048, 32,
                                               (float*)d_out, 2048, x, nullptr, nullptr);
  // 13. LN2 + FFN shift
  ln_kernel<<<BBATCH * LL, thr, 0, stream>>>((const float*)d_out, ln2_w, ln2_b, xn2);
  ffn_shift_kernel<<<4096, thr, 0, stream>>>(xn2, state, ip, ffn_maa_k, ffn_maa_r, xkb, xrb);
  // 14. batched rr + kk: grid (256,2) = 512 WGs
  f2bf_kernel<<<4096, thr, 0, stream>>>(fWr, WB0, nconv);
  f2bf_kernel<<<4096, thr, 0, stream>>>(fWk, WB1, nconv);
  gemm_ffn2<<<dim3(256, 2), thr, 0, stream>>>(xrb, xkb, WB0, WB1, rrraw, kkb);
  // 15. out += sigmoid(rr) * (kk @ fWv^T): 128x64 tiles, grid 512
  f2bf_kernel<<<4096, thr, 0, stream>>>(fWv, WB1, nconv);
  gemm_bt<3, 128, 64><<<512, thr, 0, stream>>>(kkb, 2048, WB1, 2048, 2048, 32,
                                               (float*)d_out, 2048, (const float*)d_out,
                                               rrraw, nullptr);
}

// Round 7
// 480.148 us; speedup vs baseline: 3.9765x; 1.1592x over previous
//
#include <hip/hip_runtime.h>

#define EE 2048
#define LL 512
#define BBATCH 4
#define HH 32
#define SS 64
#define EPSF 1e-5f
static constexpr size_t NEL = (size_t)BBATCH * LL * EE;  // 4,194,304

typedef __attribute__((ext_vector_type(8))) short short8;
typedef __attribute__((ext_vector_type(4))) float f32x4;

__device__ __forceinline__ unsigned short f2bf(float f) {
  union { float f; unsigned u; } x; x.f = f;
  return (unsigned short)((x.u + 0x7fffu + ((x.u >> 16) & 1u)) >> 16);
}

__device__ __forceinline__ void gload_lds16(const unsigned short* g, unsigned short* l) {
  __builtin_amdgcn_global_load_lds((const __attribute__((address_space(1))) void*)g,
                                   (__attribute__((address_space(3))) void*)l, 16, 0, 0);
}

// ---------------- batched fp32 -> bf16 conversion (up to 4 jobs) ----------------
struct CvArgs {
  const float* s[4];
  unsigned short* d[4];
};
__global__ void __launch_bounds__(256) f2bf_batch(CvArgs a, int n4) {
  int z = blockIdx.y;
  int idx = blockIdx.x * 256 + threadIdx.x;
  if (idx >= n4) return;
  float4 v = ((const float4*)a.s[z])[idx];
  ushort4 o;
  o.x = f2bf(v.x); o.y = f2bf(v.y); o.z = f2bf(v.z); o.w = f2bf(v.w);
  ((ushort4*)a.d[z])[idx] = o;
}

// ---------------- merged weight prep: w1T, w2cat, dw1T, dw2T in one launch ----------------
__global__ void __launch_bounds__(256) wprep_kernel(const float* __restrict__ w1,
                                                    const float* __restrict__ w2,
                                                    const float* __restrict__ d1,
                                                    const float* __restrict__ d2,
                                                    unsigned short* __restrict__ w1T,
                                                    unsigned short* __restrict__ w2cat,
                                                    unsigned short* __restrict__ dw1T,
                                                    unsigned short* __restrict__ dw2T) {
  const int N0 = 256 * 2048;     // w1T
  const int N1 = 10240 * 160;    // w2cat
  const int N2 = 128 * 2048;     // dw1T
  const int N3 = 2048 * 128;     // dw2T
  int id = blockIdx.x * 256 + threadIdx.x;
  if (id < N0) {
    int n = id >> 11, k = id & 2047;
    float v = (n < 160) ? w1[(size_t)k * 160 + n] : 0.f;
    w1T[id] = f2bf(v);
    return;
  }
  id -= N0;
  if (id < N1) {
    int n = id / 160, kq = id - n * 160;
    int j = n >> 11, e = n & 2047;
    float v = ((kq >> 5) == j) ? w2[(size_t)kq * 2048 + e] : 0.f;
    w2cat[id] = f2bf(v);
    return;
  }
  id -= N1;
  if (id < N2) {
    int n = id >> 11, k = id & 2047;
    float v = (n < 64) ? d1[(size_t)k * 64 + n] : 0.f;
    dw1T[id] = f2bf(v);
    return;
  }
  id -= N2;
  if (id < N3) {
    int n = id >> 7, k = id & 127;
    float v = (k < 64) ? d2[(size_t)k * 2048 + n] : 0.f;
    dw2T[id] = f2bf(v);
  }
}

// ---------------- LayerNorm over E per token ----------------
__global__ void __launch_bounds__(256) ln_kernel(const float* __restrict__ x,
                                                 const float* __restrict__ wt,
                                                 const float* __restrict__ bs,
                                                 float* __restrict__ out) {
  __shared__ float red[4];
  int tid = threadIdx.x;
  size_t base = (size_t)blockIdx.x * EE;
  int e = tid * 8;
  float4 v0 = *(const float4*)&x[base + e];
  float4 v1 = *(const float4*)&x[base + e + 4];
  float s = v0.x + v0.y + v0.z + v0.w + v1.x + v1.y + v1.z + v1.w;
#pragma unroll
  for (int off = 32; off >= 1; off >>= 1) s += __shfl_xor(s, off);
  if ((tid & 63) == 0) red[tid >> 6] = s;
  __syncthreads();
  float mean = (red[0] + red[1] + red[2] + red[3]) * (1.f / EE);
  __syncthreads();
  float d, q = 0.f;
  d = v0.x - mean; q += d * d; d = v0.y - mean; q += d * d;
  d = v0.z - mean; q += d * d; d = v0.w - mean; q += d * d;
  d = v1.x - mean; q += d * d; d = v1.y - mean; q += d * d;
  d = v1.z - mean; q += d * d; d = v1.w - mean; q += d * d;
#pragma unroll
  for (int off = 32; off >= 1; off >>= 1) q += __shfl_xor(q, off);
  if ((tid & 63) == 0) red[tid >> 6] = q;
  __syncthreads();
  float var = (red[0] + red[1] + red[2] + red[3]) * (1.f / EE);
  float rstd = rsqrtf(var + EPSF);
  float4 w0 = *(const float4*)&wt[e], w1 = *(const float4*)&wt[e + 4];
  float4 b0 = *(const float4*)&bs[e], b1 = *(const float4*)&bs[e + 4];
  float4 o0, o1;
  o0.x = (v0.x - mean) * rstd * w0.x + b0.x;
  o0.y = (v0.y - mean) * rstd * w0.y + b0.y;
  o0.z = (v0.z - mean) * rstd * w0.z + b0.z;
  o0.w = (v0.w - mean) * rstd * w0.w + b0.w;
  o1.x = (v1.x - mean) * rstd * w1.x + b1.x;
  o1.y = (v1.y - mean) * rstd * w1.y + b1.y;
  o1.z = (v1.z - mean) * rstd * w1.z + b1.z;
  o1.w = (v1.w - mean) * rstd * w1.w + b1.w;
  *(float4*)&out[base + e] = o0;
  *(float4*)&out[base + e + 4] = o1;
}

// ---------------- token-shift: xxm bf16 + sx f32 ----------------
__global__ void __launch_bounds__(256) shift_kernel(const float* __restrict__ xn,
                                                    const float* __restrict__ state,
                                                    const int* __restrict__ ip,
                                                    const float* __restrict__ maa_x,
                                                    unsigned short* __restrict__ xxm,
                                                    float* __restrict__ sx) {
  int tok = blockIdx.x;
  int b = tok >> 9, t = tok & 511;
  int tid = threadIdx.x;
  const float* cur = xn + (size_t)tok * EE;
  const float* prev = (t == 0)
      ? (state + ((size_t)b * (2 + SS) + (size_t)(2 + SS) * (*ip) + 1) * EE)
      : (cur - EE);
  int e = tid * 8;
#pragma unroll
  for (int half = 0; half < 2; ++half) {
    int eh = e + half * 4;
    float4 c = *(const float4*)&cur[eh];
    float4 p = *(const float4*)&prev[eh];
    float4 mx = *(const float4*)&maa_x[eh];
    float4 sv;
    sv.x = p.x - c.x; sv.y = p.y - c.y; sv.z = p.z - c.z; sv.w = p.w - c.w;
    *(float4*)&sx[(size_t)tok * EE + eh] = sv;
    ushort4 xo;
    xo.x = f2bf(c.x + sv.x * mx.x);
    xo.y = f2bf(c.y + sv.y * mx.y);
    xo.z = f2bf(c.z + sv.z * mx.z);
    xo.w = f2bf(c.w + sv.w * mx.w);
    *(ushort4*)&xxm[(size_t)tok * EE + eh] = xo;
  }
}

// ---------------- GEMM core: C_tile = A[m,:K] x W[n,:K]^T, XOR-swizzled LDS ----------------
// 256 threads, 4 waves as 2x2. BK in {32,64}. Swizzle (rule #21): linear LDS dest for
// global_load_lds, inverse-swizzled GLOBAL source, swizzled ds_read.
template <int BM, int BN, int BK>
__device__ __forceinline__ void gemm_core(const unsigned short* __restrict__ A, int lda,
                                          const unsigned short* __restrict__ W, int ldw,
                                          int K, int NB, unsigned short* As, unsigned short* Bs,
                                          f32x4 (&acc)[BM / 32][BN / 32], int& m0o, int& n0o) {
  constexpr int FM = BM / 32, FN = BN / 32;
  constexpr int GPR = BK / 8;              // 16B granules per row
  constexpr int LA = BM * GPR / 256;       // granule loads per thread (A)
  constexpr int LB = BN * GPR / 256;
  int nwg = gridDim.x, bid = blockIdx.x;
  int qd = nwg >> 3;
  int wg = (bid & 7) * qd + (bid >> 3);  // bijective XCD swizzle (nwg % 8 == 0)
  int bm = wg / NB, bn = wg - bm * NB;
  int tid = threadIdx.x;
  int wave = tid >> 6, lane = tid & 63;
  int wm = wave >> 1, wn = wave & 1;
  const unsigned short* Abase = A + (size_t)bm * BM * lda;
  const unsigned short* Bbase = W + (size_t)bn * BN * ldw;
  for (int k0 = 0; k0 < K; k0 += BK) {
    __syncthreads();  // prior ds_reads done before overwrite
#pragma unroll
    for (int r = 0; r < LA; ++r) {
      int g = r * 256 + tid;
      int row = g / GPR, p = g & (GPR - 1);
      int lg = p ^ (row & (GPR - 1));  // inverse-swizzled source granule
      gload_lds16(Abase + (size_t)row * lda + k0 + lg * 8, &As[g * 8]);
    }
#pragma unroll
    for (int r = 0; r < LB; ++r) {
      int g = r * 256 + tid;
      int row = g / GPR, p = g & (GPR - 1);
      int lg = p ^ (row & (GPR - 1));
      gload_lds16(Bbase + (size_t)row * ldw + k0 + lg * 8, &Bs[g * 8]);
    }
    __syncthreads();  // drains vmcnt: LDS tile ready
    int q = lane >> 4;
    int rA = wm * (BM / 2) + (lane & 15);
    int rB = wn * (BN / 2) + (lane & 15);
    int xrA = rA & (GPR - 1), xrB = rB & (GPR - 1);  // f*16 doesn't change low bits
#pragma unroll
    for (int ks = 0; ks < BK / 32; ++ks) {
      short8 av[FM], bv[FN];
#pragma unroll
      for (int f = 0; f < FM; f++) {
        int p = (ks * 4 + q) ^ xrA;
        av[f] = *(const short8*)&As[(rA + f * 16) * BK + p * 8];
      }
#pragma unroll
      for (int f = 0; f < FN; f++) {
        int p = (ks * 4 + q) ^ xrB;
        bv[f] = *(const short8*)&Bs[(rB + f * 16) * BK + p * 8];
      }
#pragma unroll
      for (int fm = 0; fm < FM; fm++)
#pragma unroll
        for (int fn = 0; fn < FN; fn++)
          acc[fm][fn] =
              __builtin_amdgcn_mfma_f32_16x16x32_bf16(av[fm], bv[fn], acc[fm][fn], 0, 0, 0);
    }
  }
  m0o = bm * BM + wm * (BM / 2);
  n0o = bn * BN + wn * (BN / 2);
}

// epilogue: functor f(m, n, val) per owned element
template <int FM, int FN, typename F>
__device__ __forceinline__ void epi_loop(f32x4 (&acc)[FM][FN], int m0, int n0, F f) {
  int lane = threadIdx.x & 63;
  int rl = (lane >> 4) * 4, cl = lane & 15;
#pragma unroll
  for (int fm = 0; fm < FM; fm++)
#pragma unroll
    for (int fn = 0; fn < FN; fn++)
#pragma unroll
      for (int q = 0; q < 4; q++)
        f(m0 + fm * 16 + rl + q, n0 + fn * 16 + cl, acc[fm][fn][q]);
}

// MODE 2: f32 p1+acc. 3: f32 p1+sigmoid(p2)*acc. 5: bf16 tanh. 6: f32 exp(-exp(p1[n]+acc)). 7: x5.
template <int MODE, int BM, int BN, int BK>
__global__ void __launch_bounds__(256) gemm_bt(const unsigned short* __restrict__ A, int lda,
                                               const unsigned short* __restrict__ W, int ldw,
                                               int K, int NB, void* __restrict__ Cout, int ldc,
                                               const float* __restrict__ p1,
                                               const float* __restrict__ p2,
                                               const float* __restrict__ p3) {
  __shared__ __align__(16) unsigned short As[BM * BK];
  __shared__ __align__(16) unsigned short Bs[BN * BK];
  f32x4 acc[BM / 32][BN / 32] = {};
  int m0, n0;
  gemm_core<BM, BN, BK>(A, lda, W, ldw, K, NB, As, Bs, acc, m0, n0);
  epi_loop(acc, m0, n0, [&](int m, int n, float val) {
    size_t o = (size_t)m * ldc + n;
    if constexpr (MODE == 2) {
      ((float*)Cout)[o] = p1[o] + val;
    } else if constexpr (MODE == 3) {
      ((float*)Cout)[o] = p1[o] + val * (1.f / (1.f + expf(-p2[o])));
    } else if constexpr (MODE == 5) {
      ((unsigned short*)Cout)[o] = f2bf(tanhf(val));
    } else if constexpr (MODE == 6) {
      ((float*)Cout)[o] = expf(-expf(p1[n] + val));
    } else {  // MODE 7: x5 assemble: j = n>>11, e = n&2047
      int j = n >> 11, e = n & 2047;
      size_t oe = (size_t)m * EE + e;
      float xv = p1[oe];
      float sv = p2[oe];
      float st = p3[(size_t)j * EE + e];
      ((unsigned short*)Cout)[(size_t)j * NEL + oe] = f2bf(xv + sv * (st + val));
    }
  });
}

// ---- batched 4-GEMM (k,v,r,g projections); z = blockIdx.y; z==3 -> silu ----
struct Proj4Args {
  const unsigned short* A[4];
  const unsigned short* W[4];
  float* C[4];
};
__global__ void __launch_bounds__(256) gemm_proj4(Proj4Args args) {
  __shared__ __align__(16) unsigned short As[128 * 64];
  __shared__ __align__(16) unsigned short Bs[128 * 64];
  int z = blockIdx.y;
  f32x4 acc[4][4] = {};
  int m0, n0;
  gemm_core<128, 128, 64>(args.A[z], EE, args.W[z], EE, EE, 16, As, Bs, acc, m0, n0);
  float* C = args.C[z];
  bool silu = (z == 3);
  epi_loop(acc, m0, n0, [&](int m, int n, float val) {
    size_t o = (size_t)m * EE + n;
    C[o] = silu ? (val / (1.f + expf(-val))) : val;
  });
}

// ---- batched 2-GEMM (rr f32 ; kk = relu^2 bf16); z = blockIdx.y ----
__global__ void __launch_bounds__(256) gemm_ffn2(const unsigned short* A0,
                                                 const unsigned short* A1,
                                                 const unsigned short* W0,
                                                 const unsigned short* W1, float* C0,
                                                 unsigned short* C1) {
  __shared__ __align__(16) unsigned short As[128 * 64];
  __shared__ __align__(16) unsigned short Bs[128 * 64];
  int z = blockIdx.y;
  f32x4 acc[4][4] = {};
  int m0, n0;
  gemm_core<128, 128, 64>(z ? A1 : A0, EE, z ? W1 : W0, EE, EE, 16, As, Bs, acc, m0, n0);
  epi_loop(acc, m0, n0, [&](int m, int n, float val) {
    size_t o = (size_t)m * EE + n;
    if (z == 0) {
      C0[o] = val;
    } else {
      float rv = fmaxf(val, 0.f);
      C1[o] = f2bf(rv * rv);
    }
  });
}

// ---------------- WKV scan v5: 2 blocks per head (k-split), atomicAdd combine ----------------
__global__ void __launch_bounds__(512) scan_kernel(const float* __restrict__ r,
                                                   const float* __restrict__ k,
                                                   const float* __restrict__ v,
                                                   const float* __restrict__ w,
                                                   const float* __restrict__ state,
                                                   const float* __restrict__ faaaa,
                                                   const int* __restrict__ ip,
                                                   float* __restrict__ att) {
  __shared__ float bR[2][8][32], bK[2][8][32], bW[2][8][32];
  __shared__ float bV[2][8][64];
  __shared__ float part[8][8][64];  // [t][wave][d]
  int blk = blockIdx.x;
  int bh = blk >> 1, kh = blk & 1;
  int b = bh >> 5, h = bh & 31;
  int tid = threadIdx.x, wv = tid >> 6, lane = tid & 63;
  int klocal = wv * 4;
  int k0w = kh * 32 + klocal;
  int ii = *ip;
  const float* sb = state + ((size_t)b * (2 + SS) + (size_t)(2 + SS) * ii + 2) * EE;
  float s_[4], u_[4];
#pragma unroll
  for (int q = 0; q < 4; ++q) {
    int kk_ = k0w + q;
    s_[q] = sb[(size_t)(2 * h + (kk_ >> 5)) * EE + (kk_ & 31) * 64 + lane];
    u_[q] = faaaa[h * 64 + kk_];
  }
  size_t base = (size_t)b * LL * EE + (size_t)h * 64;
  int c = tid;
  bool ld = c < 320;
  int lt = c / 40, r40 = c - lt * 40;
  int la = (r40 < 24) ? (r40 >> 3) : 3;  // 0=r 1=k 2=w 3=v
  int lcG = (r40 < 24) ? (kh * 32 + (r40 & 7) * 4) : ((r40 - 24) * 4);
  int lcL = (r40 < 24) ? ((r40 & 7) * 4) : ((r40 - 24) * 4);
  const float* lsrc = nullptr;
  if (ld) {
    const float* arr = (la == 0) ? r : (la == 1) ? k : (la == 2) ? w : v;
    lsrc = arr + base + (size_t)lt * EE + lcG;
    float4 v0 = *(const float4*)lsrc;
    if (la == 0) *(float4*)&bR[0][lt][lcL] = v0;
    else if (la == 1) *(float4*)&bK[0][lt][lcL] = v0;
    else if (la == 2) *(float4*)&bW[0][lt][lcL] = v0;
    else *(float4*)&bV[0][lt][lcL] = v0;
  }
  __syncthreads();
  for (int g = 0; g < 64; ++g) {
    int cb = g & 1;
    float4 nv;
    if (ld && g < 63) nv = *(const float4*)(lsrc + (size_t)(g + 1) * 8 * EE);
#pragma unroll
    for (int t = 0; t < 8; ++t) {
      float vv = bV[cb][t][lane];
      float acc = 0.f;
#pragma unroll
      for (int q = 0; q < 4; ++q) {
        float rk = bR[cb][t][klocal + q];
        float kk2 = bK[cb][t][klocal + q];
        float wk = bW[cb][t][klocal + q];
        float a = kk2 * vv;
        acc = fmaf(rk, fmaf(u_[q], a, s_[q]), acc);
        s_[q] = fmaf(wk, s_[q], a);
      }
      part[t][wv][lane] = acc;
    }
    if (ld && g < 63) {
      int nb = cb ^ 1;
      if (la == 0) *(float4*)&bR[nb][lt][lcL] = nv;
      else if (la == 1) *(float4*)&bK[nb][lt][lcL] = nv;
      else if (la == 2) *(float4*)&bW[nb][lt][lcL] = nv;
      else *(float4*)&bV[nb][lt][lcL] = nv;
    }
    __syncthreads();
    {
      int t = tid >> 6, d = tid & 63;
      float tot = part[t][0][d] + part[t][1][d] + part[t][2][d] + part[t][3][d] +
                  part[t][4][d] + part[t][5][d] + part[t][6][d] + part[t][7][d];
      atomicAdd(&att[base + (size_t)(g * 8 + t) * EE + d], tot);
    }
    __syncthreads();
  }
}

// ---------------- GroupNorm (per head) + gate, out bf16 ----------------
__global__ void __launch_bounds__(256) gn_gate_kernel(const float* __restrict__ att,
                                                      const float* __restrict__ g,
                                                      const float* __restrict__ gnw,
                                                      const float* __restrict__ gnb,
                                                      unsigned short* __restrict__ attg) {
  int tok = blockIdx.x, tid = threadIdx.x;
  int h = tid >> 3, j = tid & 7;
  size_t base = (size_t)tok * EE + h * 64 + j * 8;
  int e = h * 64 + j * 8;
  float4 a0 = *(const float4*)&att[base];
  float4 a1 = *(const float4*)&att[base + 4];
  float s = a0.x + a0.y + a0.z + a0.w + a1.x + a1.y + a1.z + a1.w;
  s += __shfl_xor(s, 1); s += __shfl_xor(s, 2); s += __shfl_xor(s, 4);
  float mean = s * (1.f / 64.f);
  float d, q = 0.f;
  d = a0.x - mean; q += d * d; d = a0.y - mean; q += d * d;
  d = a0.z - mean; q += d * d; d = a0.w - mean; q += d * d;
  d = a1.x - mean; q += d * d; d = a1.y - mean; q += d * d;
  d = a1.z - mean; q += d * d; d = a1.w - mean; q += d * d;
  q += __shfl_xor(q, 1); q += __shfl_xor(q, 2); q += __shfl_xor(q, 4);
  float rstd = rsqrtf(q * (1.f / 64.f) + EPSF);
  float4 w0 = *(const float4*)&gnw[e], w1 = *(const float4*)&gnw[e + 4];
  float4 b0 = *(const float4*)&gnb[e], b1 = *(const float4*)&gnb[e + 4];
  float4 g0 = *(const float4*)&g[base], g1 = *(const float4*)&g[base + 4];
  ushort4 o0, o1;
  o0.x = f2bf(((a0.x - mean) * rstd * w0.x + b0.x) * g0.x);
  o0.y = f2bf(((a0.y - mean) * rstd * w0.y + b0.y) * g0.y);
  o0.z = f2bf(((a0.z - mean) * rstd * w0.z + b0.z) * g0.z);
  o0.w = f2bf(((a0.w - mean) * rstd * w0.w + b0.w) * g0.w);
  o1.x = f2bf(((a1.x - mean) * rstd * w1.x + b1.x) * g1.x);
  o1.y = f2bf(((a1.y - mean) * rstd * w1.y + b1.y) * g1.y);
  o1.z = f2bf(((a1.z - mean) * rstd * w1.z + b1.z) * g1.z);
  o1.w = f2bf(((a1.w - mean) * rstd * w1.w + b1.w) * g1.w);
  *(ushort4*)&attg[base] = o0;
  *(ushort4*)&attg[base + 4] = o1;
}

// ---------------- FFN token-shift, out bf16 xk/xr ----------------
__global__ void __launch_bounds__(256) ffn_shift_kernel(const float* __restrict__ xn2,
                                                        const float* __restrict__ state,
                                                        const int* __restrict__ ip,
                                                        const float* __restrict__ mk,
                                                        const float* __restrict__ mr,
                                                        unsigned short* __restrict__ xkb,
                                                        unsigned short* __restrict__ xrb) {
  size_t i4 = (size_t)blockIdx.x * 256 + threadIdx.x;
  size_t e0 = i4 * 4;
  if (e0 >= NEL) return;
  int tok = (int)(e0 >> 11);
  int c = (int)(e0 & 2047);
  int b = tok >> 9, t = tok & 511;
  float4 cur = *(const float4*)&xn2[e0];
  float4 prev;
  if (t == 0) {
    int ii = *ip;
    prev = *(const float4*)&state[((size_t)b * (2 + SS) + (size_t)(2 + SS) * ii + 0) * EE + c];
  } else {
    prev = *(const float4*)&xn2[e0 - EE];
  }
  float4 k4 = *(const float4*)&mk[c];
  float4 r4 = *(const float4*)&mr[c];
  ushort4 ko, ro;
  ko.x = f2bf(cur.x + (prev.x - cur.x) * k4.x);
  ko.y = f2bf(cur.y + (prev.y - cur.y) * k4.y);
  ko.z = f2bf(cur.z + (prev.z - cur.z) * k4.z);
  ko.w = f2bf(cur.w + (prev.w - cur.w) * k4.w);
  ro.x = f2bf(cur.x + (prev.x - cur.x) * r4.x);
  ro.y = f2bf(cur.y + (prev.y - cur.y) * r4.y);
  ro.z = f2bf(cur.z + (prev.z - cur.z) * r4.z);
  ro.w = f2bf(cur.w + (prev.w - cur.w) * r4.w);
  *(ushort4*)&xkb[e0] = ko;
  *(ushort4*)&xrb[e0] = ro;
}

extern "C" void kernel_launch(void* const* d_in, const int* in_sizes, int n_in,
                              void* d_out, int out_size, void* d_ws, size_t ws_size,
                              hipStream_t stream) {
  const float* x = (const float*)d_in[0];
  const float* state = (const float*)d_in[1];
  const float* ln1_w = (const float*)d_in[2];
  const float* ln1_b = (const float*)d_in[3];
  const float* ln2_w = (const float*)d_in[4];
  const float* ln2_b = (const float*)d_in[5];
  const float* maa_x = (const float*)d_in[6];
  const float* maa_w1 = (const float*)d_in[7];
  const float* maa_w2 = (const float*)d_in[8];
  const float* maa_stack = (const float*)d_in[9];
  const float* time_decay = (const float*)d_in[10];
  const float* decay_w1 = (const float*)d_in[11];
  const float* decay_w2 = (const float*)d_in[12];
  const float* faaaa = (const float*)d_in[13];
  const float* Wr = (const float*)d_in[14];
  const float* Wk = (const float*)d_in[15];
  const float* Wv = (const float*)d_in[16];
  const float* Wg = (const float*)d_in[17];
  const float* Wo = (const float*)d_in[18];
  const float* gn_w = (const float*)d_in[19];
  const float* gn_b = (const float*)d_in[20];
  const float* ffn_maa_k = (const float*)d_in[21];
  const float* ffn_maa_r = (const float*)d_in[22];
  const float* fWk = (const float*)d_in[23];
  const float* fWr = (const float*)d_in[24];
  const float* fWv = (const float*)d_in[25];
  const int* ip = (const int*)d_in[26];

  char* ws = (char*)d_ws;
  const size_t MB1 = 1024 * 1024;
  unsigned short* WB0 = (unsigned short*)ws;                       // 8 MB
  unsigned short* WB1 = (unsigned short*)(ws + 8 * MB1);           // 8 MB
  float* xn = (float*)(ws + 16 * MB1);                             // 16 MB (also WB2/WB3, att)
  unsigned short* x5b = (unsigned short*)(ws + 32 * MB1);          // 5 x 8 MB
  float* wbuf = (float*)(ws + 72 * MB1);                           // 16 MB (xxm in low 8)
  float* rbuf = (float*)(ws + 88 * MB1);                           // 16 MB
  float* kbuf = (float*)(ws + 104 * MB1);                          // 16 MB (fWv late)
  float* vbuf = (float*)(ws + 120 * MB1);                          // 16 MB
  float* gbuf = (float*)(ws + 136 * MB1);                          // 16 MB (sx first)
  char* smalls = ws + 152 * MB1;                                   // ~6.8 MB
  unsigned short* th = (unsigned short*)smalls;                    // 1 MB
  unsigned short* w1T = (unsigned short*)(smalls + 1 * MB1);       // 1 MB
  unsigned short* w2cat = (unsigned short*)(smalls + 2 * MB1);     // 3.28 MB
  unsigned short* dw1T = (unsigned short*)(smalls + 5376 * 1024);  // 0.5 MB
  unsigned short* dw2T = (unsigned short*)(smalls + 5888 * 1024);  // 0.5 MB
  unsigned short* dt = (unsigned short*)(smalls + 6400 * 1024);    // 0.5 MB

  unsigned short* xxm = (unsigned short*)wbuf;
  float* sx = gbuf;
  float* att = xn;
  unsigned short* WB2 = (unsigned short*)xn;  // xn dead after x5 assemble
  unsigned short* WB3 = WB2 + NEL;
  unsigned short* attg = x5b;               // slot0
  float* xn2 = rbuf;
  unsigned short* xkb = x5b + 1 * NEL;      // slot1
  unsigned short* xrb = x5b + 2 * NEL;      // slot2
  unsigned short* kkb = x5b + 3 * NEL;      // slot3
  unsigned short* fWkB = x5b + 4 * NEL;     // slot4 (dead after proj4)
  unsigned short* fWvB = (unsigned short*)kbuf;  // dead after scan
  float* rrraw = wbuf;

  const int thr = 256;
  const int nconv = (int)(NEL / 4);

  // 1. LN1 + token shift
  ln_kernel<<<BBATCH * LL, thr, 0, stream>>>(x, ln1_w, ln1_b, xn);
  shift_kernel<<<BBATCH * LL, thr, 0, stream>>>(xn, state, ip, maa_x, xxm, sx);
  // 2. merged weight preps (w1T, w2cat, dw1T, dw2T)
  wprep_kernel<<<10496, thr, 0, stream>>>(maa_w1, maa_w2, decay_w1, decay_w2, w1T, w2cat,
                                          dw1T, dw2T);
  // 3. th = tanh(xxm @ w1T)
  gemm_bt<5, 64, 64, 64><<<128, thr, 0, stream>>>(xxm, 2048, w1T, 2048, 2048, 4, th, 256,
                                                  nullptr, nullptr, nullptr);
  // 4. x5 assemble: N=10240, K=160 (BK=32)
  gemm_bt<7, 128, 128, 32><<<1280, thr, 0, stream>>>(th, 256, w2cat, 160, 160, 80, x5b, 0,
                                                     xn, sx, maa_stack);
  // 5. dt = tanh(x5_1 @ dw1T)
  gemm_bt<5, 64, 64, 64><<<64, thr, 0, stream>>>(x5b + 1 * NEL, 2048, dw1T, 2048, 2048, 2,
                                                 dt, 128, nullptr, nullptr, nullptr);
  // 6. w = exp(-exp(td + dt @ dw2T)): K=128
  gemm_bt<6, 128, 128, 64><<<256, thr, 0, stream>>>(dt, 128, dw2T, 128, 128, 16, wbuf, 2048,
                                                    time_decay, nullptr, nullptr);
  // 7. batched conversion A: Wk,Wv,Wr,Wg
  {
    CvArgs ca;
    ca.s[0] = Wk; ca.d[0] = WB0;
    ca.s[1] = Wv; ca.d[1] = WB1;
    ca.s[2] = Wr; ca.d[2] = WB2;
    ca.s[3] = Wg; ca.d[3] = WB3;
    f2bf_batch<<<dim3(4096, 4), thr, 0, stream>>>(ca, nconv);
  }
  // 8. batched k,v,r,g projections: grid (256,4)
  {
    Proj4Args pa;
    pa.A[0] = x5b + 0 * NEL; pa.W[0] = WB0; pa.C[0] = kbuf;
    pa.A[1] = x5b + 2 * NEL; pa.W[1] = WB1; pa.C[1] = vbuf;
    pa.A[2] = x5b + 3 * NEL; pa.W[2] = WB2; pa.C[2] = rbuf;
    pa.A[3] = x5b + 4 * NEL; pa.W[3] = WB3; pa.C[3] = gbuf;
    gemm_proj4<<<dim3(256, 4), thr, 0, stream>>>(pa);
  }
  // 9. batched conversion B: Wo->WB0, fWr->WB1, fWk->slot4
  {
    CvArgs cb;
    cb.s[0] = Wo; cb.d[0] = WB0;
    cb.s[1] = fWr; cb.d[1] = WB1;
    cb.s[2] = fWk; cb.d[2] = fWkB;
    cb.s[3] = fWk; cb.d[3] = fWkB;  // unused lane
    f2bf_batch<<<dim3(4096, 3), thr, 0, stream>>>(cb, nconv);
  }
  // 10. scan (atomicAdd combine -> zero att first; att overlays WB2/WB3, now dead)
  (void)hipMemsetAsync(att, 0, NEL * sizeof(float), stream);
  scan_kernel<<<256, 512, 0, stream>>>(rbuf, kbuf, vbuf, wbuf, state, faaaa, ip, att);
  // 11. conversion C: fWv -> kbuf region (dead after scan)
  {
    CvArgs cc;
    cc.s[0] = fWv; cc.d[0] = fWvB;
    cc.s[1] = fWv; cc.d[1] = fWvB;
    cc.s[2] = fWv; cc.d[2] = fWvB;
    cc.s[3] = fWv; cc.d[3] = fWvB;
    f2bf_batch<<<dim3(4096, 1), thr, 0, stream>>>(cc, nconv);
  }
  // 12. groupnorm + gate
  gn_gate_kernel<<<BBATCH * LL, thr, 0, stream>>>(att, gbuf, gn_w, gn_b, attg);
  // 13. out = x + attg @ Wo^T : 128x64 tiles
  gemm_bt<2, 128, 64, 64><<<512, thr, 0, stream>>>(attg, 2048, WB0, 2048, 2048, 32,
                                                   (float*)d_out, 2048, x, nullptr, nullptr);
  // 14. LN2 + FFN shift
  ln_kernel<<<BBATCH * LL, thr, 0, stream>>>((const float*)d_out, ln2_w, ln2_b, xn2);
  ffn_shift_kernel<<<4096, thr, 0, stream>>>(xn2, state, ip, ffn_maa_k, ffn_maa_r, xkb, xrb);
  // 15. batched rr + kk: grid (256,2)
  gemm_ffn2<<<dim3(256, 2), thr, 0, stream>>>(xrb, xkb, WB1, fWkB, rrraw, kkb);
  // 16. out += sigmoid(rr) * (kk @ fWv^T): 128x64 tiles
  gemm_bt<3, 128, 64, 64><<<512, thr, 0, stream>>>(kkb, 2048, fWvB, 2048, 2048, 32,
                                                   (float*)d_out, 2048, (const float*)d_out,
                                                   rrraw, nullptr);
}

// Round 8
// 434.951 us; speedup vs baseline: 4.3897x; 1.1039x over previous
//
#include <hip/hip_runtime.h>

#define EE 2048
#define LL 512
#define BBATCH 4
#define HH 32
#define SS 64
#define EPSF 1e-5f
static constexpr size_t NEL = (size_t)BBATCH * LL * EE;  // 4,194,304

typedef __attribute__((ext_vector_type(8))) short short8;
typedef __attribute__((ext_vector_type(4))) float f32x4;

__device__ __forceinline__ unsigned short f2bf(float f) {
  union { float f; unsigned u; } x; x.f = f;
  return (unsigned short)((x.u + 0x7fffu + ((x.u >> 16) & 1u)) >> 16);
}

__device__ __forceinline__ void gload_lds16(const unsigned short* g, unsigned short* l) {
  __builtin_amdgcn_global_load_lds((const __attribute__((address_space(1))) void*)g,
                                   (__attribute__((address_space(3))) void*)l, 16, 0, 0);
}

template <int N>
__device__ __forceinline__ void wait_vmcnt_n() {
  if constexpr (N == 4) asm volatile("s_waitcnt vmcnt(4)" ::: "memory");
  else if constexpr (N == 6) asm volatile("s_waitcnt vmcnt(6)" ::: "memory");
  else if constexpr (N == 8) asm volatile("s_waitcnt vmcnt(8)" ::: "memory");
  else asm volatile("s_waitcnt vmcnt(0)" ::: "memory");
}

// ---------------- batched fp32 -> bf16 conversion (up to 4 jobs) ----------------
struct CvArgs {
  const float* s[4];
  unsigned short* d[4];
};
__global__ void __launch_bounds__(256) f2bf_batch(CvArgs a, int n4) {
  int z = blockIdx.y;
  int idx = blockIdx.x * 256 + threadIdx.x;
  if (idx >= n4) return;
  float4 v = ((const float4*)a.s[z])[idx];
  ushort4 o;
  o.x = f2bf(v.x); o.y = f2bf(v.y); o.z = f2bf(v.z); o.w = f2bf(v.w);
  ((ushort4*)a.d[z])[idx] = o;
}

// ---------------- merged weight prep: w1T, w2cat, dw1T, dw2T ----------------
__global__ void __launch_bounds__(256) wprep_kernel(const float* __restrict__ w1,
                                                    const float* __restrict__ w2,
                                                    const float* __restrict__ d1,
                                                    const float* __restrict__ d2,
                                                    unsigned short* __restrict__ w1T,
                                                    unsigned short* __restrict__ w2cat,
                                                    unsigned short* __restrict__ dw1T,
                                                    unsigned short* __restrict__ dw2T) {
  const int N0 = 256 * 2048;
  const int N1 = 10240 * 160;
  const int N2 = 128 * 2048;
  const int N3 = 2048 * 128;
  int id = blockIdx.x * 256 + threadIdx.x;
  if (id < N0) {
    int n = id >> 11, k = id & 2047;
    float v = (n < 160) ? w1[(size_t)k * 160 + n] : 0.f;
    w1T[id] = f2bf(v);
    return;
  }
  id -= N0;
  if (id < N1) {
    int n = id / 160, kq = id - n * 160;
    int j = n >> 11, e = n & 2047;
    float v = ((kq >> 5) == j) ? w2[(size_t)kq * 2048 + e] : 0.f;
    w2cat[id] = f2bf(v);
    return;
  }
  id -= N1;
  if (id < N2) {
    int n = id >> 11, k = id & 2047;
    float v = (n < 64) ? d1[(size_t)k * 64 + n] : 0.f;
    dw1T[id] = f2bf(v);
    return;
  }
  id -= N2;
  if (id < N3) {
    int n = id >> 7, k = id & 127;
    float v = (k < 64) ? d2[(size_t)k * 2048 + n] : 0.f;
    dw2T[id] = f2bf(v);
  }
}

// ---------------- fused LN + token-shift ----------------
// SIDE 0 (attn): prev state row offset 1; writes xn f32, xxm bf16 (mA=maa_x), sx f32.
// SIDE 1 (ffn): prev state row offset 0; writes o1=xk bf16 (mA), o2=xr bf16 (mB).
template <int SIDE>
__global__ void __launch_bounds__(256) ln_shift_kernel(
    const float* __restrict__ x, const float* __restrict__ state, const int* __restrict__ ip,
    const float* __restrict__ lnw, const float* __restrict__ lnb,
    const float* __restrict__ mA, const float* __restrict__ mB,
    float* __restrict__ xn_out, unsigned short* __restrict__ o1,
    float* __restrict__ sx_out, unsigned short* __restrict__ o2) {
  __shared__ float red[8];
  int tok = blockIdx.x;
  int b = tok >> 9, t = tok & 511;
  int tid = threadIdx.x;
  int e = tid * 8;
  size_t base = (size_t)tok * EE;
  float c[8], p[8];
  *(float4*)&c[0] = *(const float4*)&x[base + e];
  *(float4*)&c[4] = *(const float4*)&x[base + e + 4];
  bool hasp = (t != 0);
  if (hasp) {
    *(float4*)&p[0] = *(const float4*)&x[base - EE + e];
    *(float4*)&p[4] = *(const float4*)&x[base - EE + e + 4];
  } else {
    const float* srow = state + ((size_t)b * (2 + SS) + (size_t)(2 + SS) * (*ip) +
                                 (SIDE == 0 ? 1 : 0)) * EE;
    *(float4*)&p[0] = *(const float4*)&srow[e];
    *(float4*)&p[4] = *(const float4*)&srow[e + 4];
  }
  float sc = 0.f, sp = 0.f;
#pragma unroll
  for (int j = 0; j < 8; ++j) { sc += c[j]; sp += p[j]; }
#pragma unroll
  for (int off = 32; off >= 1; off >>= 1) {
    sc += __shfl_xor(sc, off);
    sp += __shfl_xor(sp, off);
  }
  if ((tid & 63) == 0) { red[tid >> 6] = sc; red[4 + (tid >> 6)] = sp; }
  __syncthreads();
  float mc = (red[0] + red[1] + red[2] + red[3]) * (1.f / EE);
  float mp = (red[4] + red[5] + red[6] + red[7]) * (1.f / EE);
  __syncthreads();
  float qc = 0.f, qp = 0.f;
#pragma unroll
  for (int j = 0; j < 8; ++j) {
    float dc = c[j] - mc, dp = p[j] - mp;
    qc += dc * dc; qp += dp * dp;
  }
#pragma unroll
  for (int off = 32; off >= 1; off >>= 1) {
    qc += __shfl_xor(qc, off);
    qp += __shfl_xor(qp, off);
  }
  if ((tid & 63) == 0) { red[tid >> 6] = qc; red[4 + (tid >> 6)] = qp; }
  __syncthreads();
  float rc = rsqrtf((red[0] + red[1] + red[2] + red[3]) * (1.f / EE) + EPSF);
  float rp = rsqrtf((red[4] + red[5] + red[6] + red[7]) * (1.f / EE) + EPSF);
  float wv[8], bv[8], av[8], bv2[8];
  *(float4*)&wv[0] = *(const float4*)&lnw[e];
  *(float4*)&wv[4] = *(const float4*)&lnw[e + 4];
  *(float4*)&bv[0] = *(const float4*)&lnb[e];
  *(float4*)&bv[4] = *(const float4*)&lnb[e + 4];
  *(float4*)&av[0] = *(const float4*)&mA[e];
  *(float4*)&av[4] = *(const float4*)&mA[e + 4];
  if (SIDE == 1) {
    *(float4*)&bv2[0] = *(const float4*)&mB[e];
    *(float4*)&bv2[4] = *(const float4*)&mB[e + 4];
  }
  float cn[8], sxv[8];
#pragma unroll
  for (int j = 0; j < 8; ++j) {
    float cnj = (c[j] - mc) * rc * wv[j] + bv[j];
    float pnj = hasp ? ((p[j] - mp) * rp * wv[j] + bv[j]) : p[j];
    cn[j] = cnj;
    sxv[j] = pnj - cnj;
  }
  if constexpr (SIDE == 0) {
    *(float4*)&xn_out[base + e] = *(float4*)&cn[0];
    *(float4*)&xn_out[base + e + 4] = *(float4*)&cn[4];
    *(float4*)&sx_out[base + e] = *(float4*)&sxv[0];
    *(float4*)&sx_out[base + e + 4] = *(float4*)&sxv[4];
    ushort4 xo0, xo1;
    xo0.x = f2bf(cn[0] + sxv[0] * av[0]); xo0.y = f2bf(cn[1] + sxv[1] * av[1]);
    xo0.z = f2bf(cn[2] + sxv[2] * av[2]); xo0.w = f2bf(cn[3] + sxv[3] * av[3]);
    xo1.x = f2bf(cn[4] + sxv[4] * av[4]); xo1.y = f2bf(cn[5] + sxv[5] * av[5]);
    xo1.z = f2bf(cn[6] + sxv[6] * av[6]); xo1.w = f2bf(cn[7] + sxv[7] * av[7]);
    *(ushort4*)&o1[base + e] = xo0;
    *(ushort4*)&o1[base + e + 4] = xo1;
  } else {
    ushort4 k0, k1, r0, r1;
    k0.x = f2bf(cn[0] + sxv[0] * av[0]); k0.y = f2bf(cn[1] + sxv[1] * av[1]);
    k0.z = f2bf(cn[2] + sxv[2] * av[2]); k0.w = f2bf(cn[3] + sxv[3] * av[3]);
    k1.x = f2bf(cn[4] + sxv[4] * av[4]); k1.y = f2bf(cn[5] + sxv[5] * av[5]);
    k1.z = f2bf(cn[6] + sxv[6] * av[6]); k1.w = f2bf(cn[7] + sxv[7] * av[7]);
    r0.x = f2bf(cn[0] + sxv[0] * bv2[0]); r0.y = f2bf(cn[1] + sxv[1] * bv2[1]);
    r0.z = f2bf(cn[2] + sxv[2] * bv2[2]); r0.w = f2bf(cn[3] + sxv[3] * bv2[3]);
    r1.x = f2bf(cn[4] + sxv[4] * bv2[4]); r1.y = f2bf(cn[5] + sxv[5] * bv2[5]);
    r1.z = f2bf(cn[6] + sxv[6] * bv2[6]); r1.w = f2bf(cn[7] + sxv[7] * bv2[7]);
    *(ushort4*)&o1[base + e] = k0;
    *(ushort4*)&o1[base + e + 4] = k1;
    *(ushort4*)&o2[base + e] = r0;
    *(ushort4*)&o2[base + e + 4] = r1;
  }
}

// ---------------- GEMM: 2-deep counted-vmcnt pipeline, XOR-swizzled dbuf LDS ----------------
template <int ROWS, int BK>
__device__ __forceinline__ void stage_mat(const unsigned short* __restrict__ base, int ld,
                                          int k0, unsigned short* dst) {
  constexpr int GPR = BK / 8;
  constexpr int L = ROWS * GPR / 256;
  int tid = threadIdx.x;
#pragma unroll
  for (int r = 0; r < L; ++r) {
    int g = r * 256 + tid;
    int row = g / GPR, p = g & (GPR - 1);
    int lg = p ^ (row & (GPR - 1));  // inverse-swizzled source granule (rule #21)
    gload_lds16(base + (size_t)row * ld + k0 + lg * 8, &dst[g * 8]);
  }
}

template <int BM, int BN, int BK>
__device__ __forceinline__ void gemm_core(const unsigned short* __restrict__ A, int lda,
                                          const unsigned short* __restrict__ W, int ldw,
                                          int K, int NB, unsigned short* AsAll,
                                          unsigned short* BsAll,
                                          f32x4 (&acc)[BM / 32][BN / 32], int& m0o, int& n0o) {
  constexpr int FM = BM / 32, FN = BN / 32, KS = BK / 32;
  constexpr int GPR = BK / 8;
  constexpr int NLD = (BM + BN) * GPR / 256;  // gload_lds per tile per thread
  int nwg = gridDim.x, bid = blockIdx.x;
  int qd = nwg >> 3;
  int wg = (bid & 7) * qd + (bid >> 3);  // bijective XCD swizzle (nwg % 8 == 0)
  int bm = wg / NB, bn = wg - bm * NB;
  int tid = threadIdx.x;
  int wave = tid >> 6, lane = tid & 63;
  int wm = wave >> 1, wn = wave & 1;
  const unsigned short* Abase = A + (size_t)bm * BM * lda;
  const unsigned short* Bbase = W + (size_t)bn * BN * ldw;
  const int T = K / BK;
  // prologue: stage tiles 0 and 1
  stage_mat<BM, BK>(Abase, lda, 0, AsAll);
  stage_mat<BN, BK>(Bbase, ldw, 0, BsAll);
  {
    int k1 = (T > 1) ? BK : 0;
    stage_mat<BM, BK>(Abase, lda, k1, AsAll + BM * BK);
    stage_mat<BN, BK>(Bbase, ldw, k1, BsAll + BN * BK);
  }
  int q = lane >> 4;
  int rA = wm * (BM / 2) + (lane & 15);
  int rB = wn * (BN / 2) + (lane & 15);
  int xrA = rA & (GPR - 1), xrB = rB & (GPR - 1);
  for (int t = 0; t < T; ++t) {
    unsigned short* As = AsAll + (t & 1) * (BM * BK);
    unsigned short* Bs = BsAll + (t & 1) * (BN * BK);
    wait_vmcnt_n<NLD>();               // my tile-t loads landed; tile t+1 stays in flight
    __builtin_amdgcn_s_barrier();      // everyone's tile t is in LDS
    __builtin_amdgcn_sched_barrier(0);
    short8 av[KS][FM], bv[KS][FN];
#pragma unroll
    for (int ks = 0; ks < KS; ++ks) {
#pragma unroll
      for (int f = 0; f < FM; f++) {
        int p = (ks * 4 + q) ^ xrA;
        av[ks][f] = *(const short8*)&As[(rA + f * 16) * BK + p * 8];
      }
#pragma unroll
      for (int f = 0; f < FN; f++) {
        int p = (ks * 4 + q) ^ xrB;
        bv[ks][f] = *(const short8*)&Bs[(rB + f * 16) * BK + p * 8];
      }
    }
    asm volatile("s_waitcnt lgkmcnt(0)" ::: "memory");  // my reads complete
    __builtin_amdgcn_sched_barrier(0);
    __builtin_amdgcn_s_barrier();      // all waves done reading this buffer
    int tn = t + 2;
    if (tn >= T) tn -= T;              // stale restage keeps vmcnt count uniform
    stage_mat<BM, BK>(Abase, lda, tn * BK, As);
    stage_mat<BN, BK>(Bbase, ldw, tn * BK, Bs);
    __builtin_amdgcn_s_setprio(1);
#pragma unroll
    for (int ks = 0; ks < KS; ++ks)
#pragma unroll
      for (int fm = 0; fm < FM; fm++)
#pragma unroll
        for (int fn = 0; fn < FN; fn++)
          acc[fm][fn] = __builtin_amdgcn_mfma_f32_16x16x32_bf16(av[ks][fm], bv[ks][fn],
                                                                acc[fm][fn], 0, 0, 0);
    __builtin_amdgcn_s_setprio(0);
  }
  m0o = bm * BM + wm * (BM / 2);
  n0o = bn * BN + wn * (BN / 2);
}

// epilogue: functor f(m, n, val) per owned element
template <int FM, int FN, typename F>
__device__ __forceinline__ void epi_loop(f32x4 (&acc)[FM][FN], int m0, int n0, F f) {
  int lane = threadIdx.x & 63;
  int rl = (lane >> 4) * 4, cl = lane & 15;
#pragma unroll
  for (int fm = 0; fm < FM; fm++)
#pragma unroll
    for (int fn = 0; fn < FN; fn++)
#pragma unroll
      for (int q = 0; q < 4; q++)
        f(m0 + fm * 16 + rl + q, n0 + fn * 16 + cl, acc[fm][fn][q]);
}

// MODE 2: f32 p1+acc. 3: f32 p1+sigmoid(p2)*acc. 5: bf16 tanh. 6: f32 exp(-exp(p1[n]+acc)). 7: x5.
template <int MODE, int BM, int BN, int BK>
__global__ void __launch_bounds__(256) gemm_bt(const unsigned short* __restrict__ A, int lda,
                                               const unsigned short* __restrict__ W, int ldw,
                                               int K, int NB, void* __restrict__ Cout, int ldc,
                                               const float* __restrict__ p1,
                                               const float* __restrict__ p2,
                                               const float* __restrict__ p3) {
  __shared__ __align__(16) unsigned short As[2 * BM * BK];
  __shared__ __align__(16) unsigned short Bs[2 * BN * BK];
  f32x4 acc[BM / 32][BN / 32] = {};
  int m0, n0;
  gemm_core<BM, BN, BK>(A, lda, W, ldw, K, NB, As, Bs, acc, m0, n0);
  epi_loop(acc, m0, n0, [&](int m, int n, float val) {
    size_t o = (size_t)m * ldc + n;
    if constexpr (MODE == 2) {
      ((float*)Cout)[o] = p1[o] + val;
    } else if constexpr (MODE == 3) {
      ((float*)Cout)[o] = p1[o] + val * (1.f / (1.f + expf(-p2[o])));
    } else if constexpr (MODE == 5) {
      ((unsigned short*)Cout)[o] = f2bf(tanhf(val));
    } else if constexpr (MODE == 6) {
      ((float*)Cout)[o] = expf(-expf(p1[n] + val));
    } else {  // MODE 7: x5 assemble
      int j = n >> 11, e = n & 2047;
      size_t oe = (size_t)m * EE + e;
      float xv = p1[oe];
      float sv = p2[oe];
      float st = p3[(size_t)j * EE + e];
      ((unsigned short*)Cout)[(size_t)j * NEL + oe] = f2bf(xv + sv * (st + val));
    }
  });
}

// ---- batched 4-GEMM (k,v,r,g projections); z==3 -> silu ----
struct Proj4Args {
  const unsigned short* A[4];
  const unsigned short* W[4];
  float* C[4];
};
__global__ void __launch_bounds__(256) gemm_proj4(Proj4Args args) {
  __shared__ __align__(16) unsigned short As[2 * 128 * 64];
  __shared__ __align__(16) unsigned short Bs[2 * 128 * 64];
  int z = blockIdx.y;
  f32x4 acc[4][4] = {};
  int m0, n0;
  gemm_core<128, 128, 64>(args.A[z], EE, args.W[z], EE, EE, 16, As, Bs, acc, m0, n0);
  float* C = args.C[z];
  bool silu = (z == 3);
  epi_loop(acc, m0, n0, [&](int m, int n, float val) {
    size_t o = (size_t)m * EE + n;
    C[o] = silu ? (val / (1.f + expf(-val))) : val;
  });
}

// ---- batched 2-GEMM (rr f32 ; kk = relu^2 bf16) ----
__global__ void __launch_bounds__(256) gemm_ffn2(const unsigned short* A0,
                                                 const unsigned short* A1,
                                                 const unsigned short* W0,
                                                 const unsigned short* W1, float* C0,
                                                 unsigned short* C1) {
  __shared__ __align__(16) unsigned short As[2 * 128 * 64];
  __shared__ __align__(16) unsigned short Bs[2 * 128 * 64];
  int z = blockIdx.y;
  f32x4 acc[4][4] = {};
  int m0, n0;
  gemm_core<128, 128, 64>(z ? A1 : A0, EE, z ? W1 : W0, EE, EE, 16, As, Bs, acc, m0, n0);
  epi_loop(acc, m0, n0, [&](int m, int n, float val) {
    size_t o = (size_t)m * EE + n;
    if (z == 0) {
      C0[o] = val;
    } else {
      float rv = fmaxf(val, 0.f);
      C1[o] = f2bf(rv * rv);
    }
  });
}

// ---------------- WKV scan v5: 2 blocks per head (k-split), atomicAdd combine ----------------
__global__ void __launch_bounds__(512) scan_kernel(const float* __restrict__ r,
                                                   const float* __restrict__ k,
                                                   const float* __restrict__ v,
                                                   const float* __restrict__ w,
                                                   const float* __restrict__ state,
                                                   const float* __restrict__ faaaa,
                                                   const int* __restrict__ ip,
                                                   float* __restrict__ att) {
  __shared__ float bR[2][8][32], bK[2][8][32], bW[2][8][32];
  __shared__ float bV[2][8][64];
  __shared__ float part[8][8][64];
  int blk = blockIdx.x;
  int bh = blk >> 1, kh = blk & 1;
  int b = bh >> 5, h = bh & 31;
  int tid = threadIdx.x, wv = tid >> 6, lane = tid & 63;
  int klocal = wv * 4;
  int k0w = kh * 32 + klocal;
  int ii = *ip;
  const float* sb = state + ((size_t)b * (2 + SS) + (size_t)(2 + SS) * ii + 2) * EE;
  float s_[4], u_[4];
#pragma unroll
  for (int q = 0; q < 4; ++q) {
    int kk_ = k0w + q;
    s_[q] = sb[(size_t)(2 * h + (kk_ >> 5)) * EE + (kk_ & 31) * 64 + lane];
    u_[q] = faaaa[h * 64 + kk_];
  }
  size_t base = (size_t)b * LL * EE + (size_t)h * 64;
  int c = tid;
  bool ld = c < 320;
  int lt = c / 40, r40 = c - lt * 40;
  int la = (r40 < 24) ? (r40 >> 3) : 3;
  int lcG = (r40 < 24) ? (kh * 32 + (r40 & 7) * 4) : ((r40 - 24) * 4);
  int lcL = (r40 < 24) ? ((r40 & 7) * 4) : ((r40 - 24) * 4);
  const float* lsrc = nullptr;
  if (ld) {
    const float* arr = (la == 0) ? r : (la == 1) ? k : (la == 2) ? w : v;
    lsrc = arr + base + (size_t)lt * EE + lcG;
    float4 v0 = *(const float4*)lsrc;
    if (la == 0) *(float4*)&bR[0][lt][lcL] = v0;
    else if (la == 1) *(float4*)&bK[0][lt][lcL] = v0;
    else if (la == 2) *(float4*)&bW[0][lt][lcL] = v0;
    else *(float4*)&bV[0][lt][lcL] = v0;
  }
  __syncthreads();
  for (int g = 0; g < 64; ++g) {
    int cb = g & 1;
    float4 nv;
    if (ld && g < 63) nv = *(const float4*)(lsrc + (size_t)(g + 1) * 8 * EE);
#pragma unroll
    for (int t = 0; t < 8; ++t) {
      float vv = bV[cb][t][lane];
      float acc = 0.f;
#pragma unroll
      for (int q = 0; q < 4; ++q) {
        float rk = bR[cb][t][klocal + q];
        float kk2 = bK[cb][t][klocal + q];
        float wk = bW[cb][t][klocal + q];
        float a = kk2 * vv;
        acc = fmaf(rk, fmaf(u_[q], a, s_[q]), acc);
        s_[q] = fmaf(wk, s_[q], a);
      }
      part[t][wv][lane] = acc;
    }
    if (ld && g < 63) {
      int nb = cb ^ 1;
      if (la == 0) *(float4*)&bR[nb][lt][lcL] = nv;
      else if (la == 1) *(float4*)&bK[nb][lt][lcL] = nv;
      else if (la == 2) *(float4*)&bW[nb][lt][lcL] = nv;
      else *(float4*)&bV[nb][lt][lcL] = nv;
    }
    __syncthreads();
    {
      int t = tid >> 6, d = tid & 63;
      float tot = part[t][0][d] + part[t][1][d] + part[t][2][d] + part[t][3][d] +
                  part[t][4][d] + part[t][5][d] + part[t][6][d] + part[t][7][d];
      atomicAdd(&att[base + (size_t)(g * 8 + t) * EE + d], tot);
    }
    __syncthreads();
  }
}

// ---------------- GroupNorm (per head) + gate, out bf16 ----------------
__global__ void __launch_bounds__(256) gn_gate_kernel(const float* __restrict__ att,
                                                      const float* __restrict__ g,
                                                      const float* __restrict__ gnw,
                                                      const float* __restrict__ gnb,
                                                      unsigned short* __restrict__ attg) {
  int tok = blockIdx.x, tid = threadIdx.x;
  int h = tid >> 3, j = tid & 7;
  size_t base = (size_t)tok * EE + h * 64 + j * 8;
  int e = h * 64 + j * 8;
  float4 a0 = *(const float4*)&att[base];
  float4 a1 = *(const float4*)&att[base + 4];
  float s = a0.x + a0.y + a0.z + a0.w + a1.x + a1.y + a1.z + a1.w;
  s += __shfl_xor(s, 1); s += __shfl_xor(s, 2); s += __shfl_xor(s, 4);
  float mean = s * (1.f / 64.f);
  float d, q = 0.f;
  d = a0.x - mean; q += d * d; d = a0.y - mean; q += d * d;
  d = a0.z - mean; q += d * d; d = a0.w - mean; q += d * d;
  d = a1.x - mean; q += d * d; d = a1.y - mean; q += d * d;
  d = a1.z - mean; q += d * d; d = a1.w - mean; q += d * d;
  q += __shfl_xor(q, 1); q += __shfl_xor(q, 2); q += __shfl_xor(q, 4);
  float rstd = rsqrtf(q * (1.f / 64.f) + EPSF);
  float4 w0 = *(const float4*)&gnw[e], w1 = *(const float4*)&gnw[e + 4];
  float4 b0 = *(const float4*)&gnb[e], b1 = *(const float4*)&gnb[e + 4];
  float4 g0 = *(const float4*)&g[base], g1 = *(const float4*)&g[base + 4];
  ushort4 o0, o1;
  o0.x = f2bf(((a0.x - mean) * rstd * w0.x + b0.x) * g0.x);
  o0.y = f2bf(((a0.y - mean) * rstd * w0.y + b0.y) * g0.y);
  o0.z = f2bf(((a0.z - mean) * rstd * w0.z + b0.z) * g0.z);
  o0.w = f2bf(((a0.w - mean) * rstd * w0.w + b0.w) * g0.w);
  o1.x = f2bf(((a1.x - mean) * rstd * w1.x + b1.x) * g1.x);
  o1.y = f2bf(((a1.y - mean) * rstd * w1.y + b1.y) * g1.y);
  o1.z = f2bf(((a1.z - mean) * rstd * w1.z + b1.z) * g1.z);
  o1.w = f2bf(((a1.w - mean) * rstd * w1.w + b1.w) * g1.w);
  *(ushort4*)&attg[base] = o0;
  *(ushort4*)&attg[base + 4] = o1;
}

extern "C" void kernel_launch(void* const* d_in, const int* in_sizes, int n_in,
                              void* d_out, int out_size, void* d_ws, size_t ws_size,
                              hipStream_t stream) {
  const float* x = (const float*)d_in[0];
  const float* state = (const float*)d_in[1];
  const float* ln1_w = (const float*)d_in[2];
  const float* ln1_b = (const float*)d_in[3];
  const float* ln2_w = (const float*)d_in[4];
  const float* ln2_b = (const float*)d_in[5];
  const float* maa_x = (const float*)d_in[6];
  const float* maa_w1 = (const float*)d_in[7];
  const float* maa_w2 = (const float*)d_in[8];
  const float* maa_stack = (const float*)d_in[9];
  const float* time_decay = (const float*)d_in[10];
  const float* decay_w1 = (const float*)d_in[11];
  const float* decay_w2 = (const float*)d_in[12];
  const float* faaaa = (const float*)d_in[13];
  const float* Wr = (const float*)d_in[14];
  const float* Wk = (const float*)d_in[15];
  const float* Wv = (const float*)d_in[16];
  const float* Wg = (const float*)d_in[17];
  const float* Wo = (const float*)d_in[18];
  const float* gn_w = (const float*)d_in[19];
  const float* gn_b = (const float*)d_in[20];
  const float* ffn_maa_k = (const float*)d_in[21];
  const float* ffn_maa_r = (const float*)d_in[22];
  const float* fWk = (const float*)d_in[23];
  const float* fWr = (const float*)d_in[24];
  const float* fWv = (const float*)d_in[25];
  const int* ip = (const int*)d_in[26];

  char* ws = (char*)d_ws;
  const size_t MB1 = 1024 * 1024;
  unsigned short* WB0 = (unsigned short*)ws;                       // 8 MB
  unsigned short* WB1 = (unsigned short*)(ws + 8 * MB1);           // 8 MB
  float* xn = (float*)(ws + 16 * MB1);                             // 16 MB (also WB2/WB3, att)
  unsigned short* x5b = (unsigned short*)(ws + 32 * MB1);          // 5 x 8 MB
  float* wbuf = (float*)(ws + 72 * MB1);                           // 16 MB (xxm in low 8)
  float* rbuf = (float*)(ws + 88 * MB1);                           // 16 MB
  float* kbuf = (float*)(ws + 104 * MB1);                          // 16 MB (fWv late)
  float* vbuf = (float*)(ws + 120 * MB1);                          // 16 MB
  float* gbuf = (float*)(ws + 136 * MB1);                          // 16 MB (sx first)
  char* smalls = ws + 152 * MB1;                                   // ~6.8 MB
  unsigned short* th = (unsigned short*)smalls;                    // 1 MB
  unsigned short* w1T = (unsigned short*)(smalls + 1 * MB1);       // 1 MB
  unsigned short* w2cat = (unsigned short*)(smalls + 2 * MB1);     // 3.28 MB
  unsigned short* dw1T = (unsigned short*)(smalls + 5376 * 1024);  // 0.5 MB
  unsigned short* dw2T = (unsigned short*)(smalls + 5888 * 1024);  // 0.5 MB
  unsigned short* dt = (unsigned short*)(smalls + 6400 * 1024);    // 0.5 MB

  unsigned short* xxm = (unsigned short*)wbuf;
  float* sx = gbuf;
  float* att = xn;
  unsigned short* WB2 = (unsigned short*)xn;  // xn dead after x5 assemble
  unsigned short* WB3 = WB2 + NEL;
  unsigned short* attg = x5b;               // slot0
  unsigned short* xkb = x5b + 1 * NEL;      // slot1
  unsigned short* xrb = x5b + 2 * NEL;      // slot2
  unsigned short* kkb = x5b + 3 * NEL;      // slot3
  unsigned short* fWkB = x5b + 4 * NEL;     // slot4 (dead after proj4)
  unsigned short* fWvB = (unsigned short*)kbuf;  // dead after scan
  float* rrraw = wbuf;

  const int thr = 256;
  const int nconv = (int)(NEL / 4);

  // 1. fused LN1 + token shift -> xn, xxm, sx
  ln_shift_kernel<0><<<BBATCH * LL, thr, 0, stream>>>(x, state, ip, ln1_w, ln1_b, maa_x,
                                                      nullptr, xn, xxm, sx, nullptr);
  // 2. merged weight preps
  wprep_kernel<<<10496, thr, 0, stream>>>(maa_w1, maa_w2, decay_w1, decay_w2, w1T, w2cat,
                                          dw1T, dw2T);
  // 3. th = tanh(xxm @ w1T)
  gemm_bt<5, 64, 64, 64><<<128, thr, 0, stream>>>(xxm, 2048, w1T, 2048, 2048, 4, th, 256,
                                                  nullptr, nullptr, nullptr);
  // 4. x5 assemble: N=10240, K=160 (BK=32, T=5)
  gemm_bt<7, 128, 128, 32><<<1280, thr, 0, stream>>>(th, 256, w2cat, 160, 160, 80, x5b, 0,
                                                     xn, sx, maa_stack);
  // 5. dt = tanh(x5_1 @ dw1T)
  gemm_bt<5, 64, 64, 64><<<64, thr, 0, stream>>>(x5b + 1 * NEL, 2048, dw1T, 2048, 2048, 2,
                                                 dt, 128, nullptr, nullptr, nullptr);
  // 6. w = exp(-exp(td + dt @ dw2T)): K=128 (T=2)
  gemm_bt<6, 128, 128, 64><<<256, thr, 0, stream>>>(dt, 128, dw2T, 128, 128, 16, wbuf, 2048,
                                                    time_decay, nullptr, nullptr);
  // 7. batched conversion A: Wk,Wv,Wr,Wg
  {
    CvArgs ca;
    ca.s[0] = Wk; ca.d[0] = WB0;
    ca.s[1] = Wv; ca.d[1] = WB1;
    ca.s[2] = Wr; ca.d[2] = WB2;
    ca.s[3] = Wg; ca.d[3] = WB3;
    f2bf_batch<<<dim3(4096, 4), thr, 0, stream>>>(ca, nconv);
  }
  // 8. batched k,v,r,g projections
  {
    Proj4Args pa;
    pa.A[0] = x5b + 0 * NEL; pa.W[0] = WB0; pa.C[0] = kbuf;
    pa.A[1] = x5b + 2 * NEL; pa.W[1] = WB1; pa.C[1] = vbuf;
    pa.A[2] = x5b + 3 * NEL; pa.W[2] = WB2; pa.C[2] = rbuf;
    pa.A[3] = x5b + 4 * NEL; pa.W[3] = WB3; pa.C[3] = gbuf;
    gemm_proj4<<<dim3(256, 4), thr, 0, stream>>>(pa);
  }
  // 9. batched conversion B: Wo->WB0, fWr->WB1, fWk->slot4
  {
    CvArgs cb;
    cb.s[0] = Wo; cb.d[0] = WB0;
    cb.s[1] = fWr; cb.d[1] = WB1;
    cb.s[2] = fWk; cb.d[2] = fWkB;
    cb.s[3] = fWk; cb.d[3] = fWkB;
    f2bf_batch<<<dim3(4096, 3), thr, 0, stream>>>(cb, nconv);
  }
  // 10. scan (atomicAdd combine -> zero att first; WB2/WB3 dead)
  (void)hipMemsetAsync(att, 0, NEL * sizeof(float), stream);
  scan_kernel<<<256, 512, 0, stream>>>(rbuf, kbuf, vbuf, wbuf, state, faaaa, ip, att);
  // 11. conversion C: fWv -> kbuf region (dead after scan)
  {
    CvArgs cc;
    cc.s[0] = fWv; cc.d[0] = fWvB;
    cc.s[1] = fWv; cc.d[1] = fWvB;
    cc.s[2] = fWv; cc.d[2] = fWvB;
    cc.s[3] = fWv; cc.d[3] = fWvB;
    f2bf_batch<<<dim3(4096, 1), thr, 0, stream>>>(cc, nconv);
  }
  // 12. groupnorm + gate
  gn_gate_kernel<<<BBATCH * LL, thr, 0, stream>>>(att, gbuf, gn_w, gn_b, attg);
  // 13. out = x + attg @ Wo^T
  gemm_bt<2, 128, 64, 64><<<512, thr, 0, stream>>>(attg, 2048, WB0, 2048, 2048, 32,
                                                   (float*)d_out, 2048, x, nullptr, nullptr);
  // 14. fused LN2 + FFN shift (reads d_out, writes xkb/xrb; no xn2 buffer)
  ln_shift_kernel<1><<<BBATCH * LL, thr, 0, stream>>>((const float*)d_out, state, ip, ln2_w,
                                                      ln2_b, ffn_maa_k, ffn_maa_r, nullptr,
                                                      xkb, nullptr, xrb);
  // 15. batched rr + kk
  gemm_ffn2<<<dim3(256, 2), thr, 0, stream>>>(xrb, xkb, WB1, fWkB, rrraw, kkb);
  // 16. out += sigmoid(rr) * (kk @ fWv^T)
  gemm_bt<3, 128, 64, 64><<<512, thr, 0, stream>>>(kkb, 2048, fWvB, 2048, 2048, 32,
                                                   (float*)d_out, 2048, (const float*)d_out,
                                                   rrraw, nullptr);
}